// Round 2
// baseline (687.258 us; speedup 1.0000x reference)
//
#include <hip/hip_runtime.h>
#include <hip/hip_bf16.h>
#include <math.h>

// ---------------------------------------------------------------------------
// Problem constants
// ---------------------------------------------------------------------------
constexpr int B = 8;
constexpr int N = 2048;
constexpr int KNN = 20;
constexpr int H = 128;
constexpr int P = 3 * N;  // 6144 pixels per batch
constexpr int QPW = 8;    // queries (waves) per knn_edge block

// ws layout (float offsets)
constexpr int OWT2   = 8448;      // W2/D2 second-half TRANSPOSED [c<128][m<256] (32768)
constexpr int OWT3   = 41216;     // W3/D3 second-half transposed (32768)
constexpr int OPS1   = 73984;     // poolsum1 shadows [8][B][128][3] = 24576
constexpr int OPS2   = 98560;     // poolsum2 shadows = 24576
constexpr int OOUTS  = 123136;    // out shadows [8][B][384] = 24576
constexpr int OBAR   = 147712;    // 3 one-shot grid-barrier counters (16 f reserved)
constexpr int OWB1   = 160000;    // Wbig1 bf16 hi/lo, FRAGMENT-MAJOR [ks][256][32h] (16384 f)
constexpr int OWB2   = 176384;    // Wbig2 fragment-major (32768 f)
constexpr int OWB3   = 209152;    // Wbig3 fragment-major (32768 f)
constexpr int OXP0   = 569600;    // Xp0 bf16 [b][P][128] (3145728 f-equiv)
// max extent ~= 8.3 MB used (weights+activations) well inside ws

constexpr int ZERO_BASE = OPS1;   // zeroed region = ps1+ps2+outs+barriers
constexpr int ZERO_CNT  = 73744;  // 73728 shadows + 16 barrier counters

constexpr int GRID_VNT  = 1024;   // 4 blocks/CU x 256 CU, exactly co-resident

typedef __attribute__((ext_vector_type(8))) short bf16x8;
typedef __attribute__((ext_vector_type(4))) float f32x4;

__device__ __forceinline__ unsigned short f2bf(float x) {
  __hip_bfloat16 h = __float2bfloat16(x);
  return *(unsigned short*)&h;
}
__device__ __forceinline__ float bf2f(unsigned short u) {
  __hip_bfloat16 h;
  *(unsigned short*)&h = u;
  return __bfloat162float(h);
}
// pack x as (hi, lo) bf16 pair in one uint (hi at lower address)
__device__ __forceinline__ unsigned int packhl(float x) {
  unsigned short hi = f2bf(x);
  float lo = x - bf2f(hi);
  unsigned short ls = f2bf(lo);
  return (unsigned)hi | ((unsigned)ls << 16);
}

// ---------------------------------------------------------------------------
// Wave-wide bitonic sort of 64 u64 keys, descending (larger key = better).
// Key = ord(value)<<32 | ~index  ==>  value desc, ties -> smaller index.
// ---------------------------------------------------------------------------
__device__ __forceinline__ void wave_sort_key(unsigned long long& k, int lane) {
#pragma unroll
  for (int kk = 2; kk <= 64; kk <<= 1) {
#pragma unroll
    for (int j = kk >> 1; j > 0; j >>= 1) {
      unsigned long long pk =
          (unsigned long long)__shfl_xor((long long)k, j);
      bool iam_lower   = (lane & j) == 0;
      bool dir_desc    = (lane & kk) == 0;
      bool p_better    = pk > k;
      bool want_better = (dir_desc == iam_lower);
      k = (p_better == want_better) ? pk : k;
    }
  }
}

// ---------------------------------------------------------------------------
// K2 (FUSED): prep + exact top-20 KNN + edge + pos layer + mean-k -> Xp0.
// (unchanged from the verified 168 us version; zero-region extended by 16 f)
// ---------------------------------------------------------------------------
__global__ __launch_bounds__(512, 8) void knn_edge_kernel(
    const float* __restrict__ pc, const float* __restrict__ Wpos,
    const float* __restrict__ Dp,
    const float* __restrict__ W1, const float* __restrict__ D1,
    const float* __restrict__ W2, const float* __restrict__ D2,
    const float* __restrict__ W3, const float* __restrict__ D3,
    float* __restrict__ ws) {
  __shared__ float4 spt[N];                       // 32 KB (2x,2y,2z,xx)
  __shared__ __align__(16) unsigned char sphase[QPW][640];   // 5 KB
  int tid = threadIdx.x;
  int b = blockIdx.y;
  int bid = blockIdx.y * gridDim.x + blockIdx.x;  // 0..2047
  int wv = tid >> 6, lane = tid & 63;
  unsigned short* Xp0 = (unsigned short*)(ws + OXP0);
  unsigned short* sbufw = (unsigned short*)sphase[wv];
  float4* erw = (float4*)sphase[wv];

  // hoisted edge-phase weight loads (latency hidden under distance pass)
  int o = lane;
  float w0 = Wpos[o * 3 + 0], w1 = Wpos[o * 3 + 1], w2 = Wpos[o * 3 + 2];
  float e0 = Dp[o * 3 + 0], e1 = Dp[o * 3 + 1], e2 = Dp[o * 3 + 2];

  // ---- folded prep: distributed shadow+barrier zeroing (1 store/thread) ---
  {
    int zi = bid * 512 + tid;
    if (zi < ZERO_CNT) ws[ZERO_BASE + zi] = 0.f;
  }
  // ---- folded prep: 768 weight rows over blocks 0..95 (one wave/row) -----
  if (bid < 96) {
    int rr = bid * 8 + wv;  // 0..767
    const float* src;
    float* tdst = nullptr;
    unsigned int* pdst;   // base of fragment-major region + m*16
    int C, Cpack;
    bool norm;
    if (rr < 128)      { src = W1 + rr * 64;            C = 64;  Cpack = 64;  norm = true;
                         pdst = (unsigned int*)(ws + OWB1) + rr * 16; }
    else if (rr < 256) { int m = rr - 128; src = D1 + m * 64;  C = 64;  Cpack = 64;  norm = false;
                         pdst = (unsigned int*)(ws + OWB1) + (m + 128) * 16; }
    else if (rr < 384) { int m = rr - 256; src = W2 + m * 256; C = 256; Cpack = 128; norm = true;
                         pdst = (unsigned int*)(ws + OWB2) + m * 16; tdst = ws + OWT2 + m; }
    else if (rr < 512) { int m = rr - 384; src = D2 + m * 256; C = 256; Cpack = 128; norm = false;
                         pdst = (unsigned int*)(ws + OWB2) + (m + 128) * 16; tdst = ws + OWT2 + 128 + m; }
    else if (rr < 640) { int m = rr - 512; src = W3 + m * 256; C = 256; Cpack = 128; norm = true;
                         pdst = (unsigned int*)(ws + OWB3) + m * 16; tdst = ws + OWT3 + m; }
    else               { int m = rr - 640; src = D3 + m * 256; C = 256; Cpack = 128; norm = false;
                         pdst = (unsigned int*)(ws + OWB3) + (m + 128) * 16; tdst = ws + OWT3 + 128 + m; }
    float s = 1.f;
    if (norm) {
      float a = 0.f;
      for (int i = lane; i < C; i += 64) a += src[i];
#pragma unroll
      for (int off = 32; off > 0; off >>= 1) a += __shfl_xor(a, off);
      s = a;
    }
    for (int i = lane; i < C; i += 64) {
      float val = src[i] / s;  // exact when s==1
      if (i < Cpack) pdst[(i >> 4) * 4096 + (i & 15)] = packhl(val);
      if (tdst && i >= 128) tdst[(i - 128) * 256] = val;
    }
  }

  // ---- stage point cloud ---------------------------------------------------
  const float* pcb = pc + (size_t)b * N * 3;
  for (int i = tid; i < N; i += 512) {
    float x = pcb[i * 3 + 0], y = pcb[i * 3 + 1], z = pcb[i * 3 + 2];
    float xx = __fadd_rn(__fadd_rn(__fmul_rn(x, x), __fmul_rn(y, y)), __fmul_rn(z, z));
    spt[i] = make_float4(2.f * x, 2.f * y, 2.f * z, xx);
  }
  __syncthreads();
  int q = blockIdx.x * QPW + wv;
  float4 qp = spt[q];
  float qx = 0.5f * qp.x, qy = 0.5f * qp.y, qz = 0.5f * qp.z, qxx = qp.w;

  float dv[32];
  float lmax = -INFINITY;
#pragma unroll
  for (int i = 0; i < 32; ++i) {
    float4 m = spt[i * 64 + lane];
    float A = __fadd_rn(__fadd_rn(__fmul_rn(m.x, qx), __fmul_rn(m.y, qy)),
                        __fmul_rn(m.z, qz));
    float d = __fsub_rn(__fsub_rn(A, qxx), m.w);
    dv[i] = d;
    lmax = fmaxf(lmax, d);
  }

  // value-only bitonic sort (descending) of the 64 lane-maxes; take #19
  float sv = lmax;
#pragma unroll
  for (int k = 2; k <= 64; k <<= 1) {
#pragma unroll
    for (int j = k >> 1; j > 0; j >>= 1) {
      float pv = __shfl_xor(sv, j);
      bool keep_max = ((lane & k) == 0) == ((lane & j) == 0);
      sv = keep_max ? fmaxf(sv, pv) : fminf(sv, pv);
    }
  }
  float tval = __shfl(sv, 19);  // 20th-largest lane-max <= V20 (provable)

  // registerized compact: per-lane survivor mask + shfl prefix scan
  unsigned msk = 0u;
#pragma unroll
  for (int i = 0; i < 32; ++i) msk |= (dv[i] >= tval) ? (1u << i) : 0u;
  int cnt = __popc(msk);
  int scan = cnt;
#pragma unroll
  for (int off = 1; off < 64; off <<= 1) {
    int t = __shfl_up(scan, off);
    scan += (lane >= off) ? t : 0;
  }
  int S = __shfl(scan, 63);
  int pos = scan - cnt;  // exclusive prefix
  unsigned mm = msk;
  while (mm) {
    int i = __ffs(mm) - 1;
    mm &= mm - 1;
    if (pos < 192) sbufw[pos] = (unsigned short)(i * 64 + lane);
    ++pos;
  }

  auto distOf = [&](int m) -> float {
    float4 mp = spt[m];
    float A = __fadd_rn(__fadd_rn(__fmul_rn(mp.x, qx), __fmul_rn(mp.y, qy)),
                        __fmul_rn(mp.z, qz));
    return __fsub_rn(__fsub_rn(A, qxx), mp.w);
  };
  auto mkkey = [&](int m) -> unsigned long long {
    float d = distOf(m);
    unsigned u = __float_as_uint(d);
    u ^= (u >> 31) ? 0xFFFFFFFFu : 0x80000000u;
    return ((unsigned long long)u << 32) | (unsigned)(~m);
  };

  unsigned long long key = 0ULL;  // padding key: below every real key
  if (S <= 64) {
    if (lane < S) key = mkkey(sbufw[lane]);
    wave_sort_key(key, lane);
  } else if (S <= 192) {
    int p2 = 0;
    while (p2 < S) {
      if (lane >= KNN) {
        int t = p2 + lane - KNN;
        key = (t < S) ? mkkey(sbufw[t]) : 0ULL;
      }
      wave_sort_key(key, lane);
      p2 += 64 - KNN;
    }
  } else {
    int p2 = 0;
    while (p2 < N) {
      if (lane >= KNN) {
        int t = p2 + lane - KNN;
        key = (t < N) ? mkkey(t) : 0ULL;
      }
      wave_sort_key(key, lane);
      p2 += 64 - KNN;
    }
  }
  int cm = ~((unsigned)key);  // valid in lanes 0..19

  // ---- edge geometry precompute: lane k<20 computes e/r once --------------
  if (lane < KNN) {
    float4 t = spt[cm];
    float nx = 0.5f * t.x, ny = 0.5f * t.y, nz = 0.5f * t.z;
    float ex = nx - qx, ey = ny - qy, ez = nz - qz;
    float rx = ny * qz - nz * qy;
    float ry = nz * qx - nx * qz;
    float rz = nx * qy - ny * qx;
    erw[2 * lane + 0] = make_float4(ex, ey, ez, 0.f);
    erw[2 * lane + 1] = make_float4(rx, ry, rz, 0.f);
  }

  // ---- edge + pos layer (lane o = channel o) -------------------------------
  {
    float s = (w0 + w2) + w1;
    w0 = w0 / s; w1 = w1 / s; w2 = w2 / s;
  }
  float cx = qx, cy = qy, cz = qz;  // exact raw coords (0.5 * 2x)
  float pcx = w1 * cx, pcy = w1 * cy, pcz = w1 * cz;
  float dcx = e1 * cx, dcy = e1 * cy, dcz = e1 * cz;
  float ax = 0.f, ay = 0.f, az = 0.f;
#pragma unroll 4
  for (int k = 0; k < KNN; ++k) {
    float4 e4 = erw[2 * k + 0];   // broadcast LDS reads
    float4 r4 = erw[2 * k + 1];
    float ex = e4.x, ey = e4.y, ez = e4.z;
    float rx = r4.x, ry = r4.y, rz = r4.z;
    float px = fmaf(w0, ex, fmaf(w2, rx, pcx));
    float py = fmaf(w0, ey, fmaf(w2, ry, pcy));
    float pz = fmaf(w0, ez, fmaf(w2, rz, pcz));
    float dx = fmaf(e0, ex, fmaf(e2, rx, dcx));
    float dy = fmaf(e0, ey, fmaf(e2, ry, dcy));
    float dz = fmaf(e0, ez, fmaf(e2, rz, dcz));
    float dot = fmaf(px, dx, fmaf(py, dy, pz * dz));
    float dns = fmaf(dx, dx, fmaf(dy, dy, dz * dz)) + 1e-6f;
    float r0 = __builtin_amdgcn_rcpf(dns);
    r0 = r0 * fmaf(-dns, r0, 2.0f);          // 1 Newton step
    float f = (dot < 0.f) ? dot * r0 : 0.f;
    ax = fmaf(-f, dx, px) + ax;
    ay = fmaf(-f, dy, py) + ay;
    az = fmaf(-f, dz, pz) + az;
  }
  int pbase = ((q >> 4) * 48) + (q & 15);
  unsigned short* dst = Xp0 + ((size_t)b * P + pbase) * 128 + 2 * o;
  *(unsigned int*)(dst)              = packhl(ax * (1.f / 20.f));
  *(unsigned int*)(dst + 16 * 128)   = packhl(ay * (1.f / 20.f));
  *(unsigned int*)(dst + 32 * 128)   = packhl(az * (1.f / 20.f));
}

// ---------------------------------------------------------------------------
// Software grid barrier (capture-safe; no cooperative launch API).
// Safe because all GRID_VNT blocks are co-resident by construction:
//   __launch_bounds__(256,4) caps VGPR<=128 (4 waves/SIMD), LDS 29952 B
//   -> exactly 4 blocks/CU x 256 CU = 1024 = GRID_VNT.
// One-shot counter per barrier instance, re-zeroed each launch by knn_edge.
// __threadfence() = device-scope fence: L2 writeback/invalidate handles
// cross-XCD visibility (atomicAdd itself is device-scope, m20).
// ---------------------------------------------------------------------------
__device__ __forceinline__ void grid_barrier(unsigned int* cnt) {
  __syncthreads();
  if (threadIdx.x == 0) {
    __threadfence();            // release our writes before signaling
    atomicAdd(cnt, 1u);
    while (__hip_atomic_load(cnt, __ATOMIC_ACQUIRE,
                             __HIP_MEMORY_SCOPE_AGENT) < (unsigned)GRID_VNT) {
      __builtin_amdgcn_s_sleep(1);
    }
  }
  __syncthreads();
  __threadfence();              // invalidate caches before reading peers' data
}

// ---------------------------------------------------------------------------
// Shared VNT layer body.
// GSRC=true : stage the X tile [48][K2] from global Xp into LDS.
// GSRC=false: the X tile is ALREADY in LDS (packed in place by the previous
//             layer, byte-identical to what staging would have produced).
// The in-place repack works because LDO*4 bytes == (256+8)*2 bytes == 528.
// ---------------------------------------------------------------------------
template <int K2, bool HASPOOL, bool LAST, bool GSRC>
__device__ __forceinline__ void vnt_layer_body(
    unsigned short* xt, float* sb, float* spool,
    const unsigned short* __restrict__ Xp, const unsigned short* __restrict__ Wb,
    const float* __restrict__ ps, const float* __restrict__ Wt,
    float* __restrict__ pool, float* __restrict__ outs,
    int b, int nt, int p0, int tid) {
  constexpr int KS = K2 / 32;
  constexpr int LDR = K2 + 8;   // halves; X-tile row stride
  constexpr int LDO = 132;      // floats; out-tile row stride
  float* ot = (float*)xt;
  int w = tid >> 6, lane = tid & 63;
  int q = lane >> 4, cl = lane & 15;

  if constexpr (GSRC) {
    // stage X tile [48][K2] -> LDS
    for (int ch = tid; ch < 48 * (K2 / 8); ch += 256) {
      int rp = ch / (K2 / 8), cc = ch % (K2 / 8);
      *(uint4*)(xt + rp * LDR + cc * 8) =
          *(const uint4*)(Xp + ((size_t)b * P + p0 + rp) * K2 + cc * 8);
    }
  }
  if constexpr (HASPOOL) {
    // pooled mean (sum of 8 shadow copies) -> LDS
    for (int i = tid; i < 384; i += 256) {
      float x = 0.f;
#pragma unroll
      for (int k = 0; k < 8; ++k) x += ps[k * 3072 + b * 384 + i];
      spool[i] = x * (1.f / 2048.f);
    }
  }

  // first A-fragments: global, LDS-independent -> issue before the barrier
  bf16x8 acur[2][2], anxt[2][2];
#pragma unroll
  for (int t = 0; t < 2; ++t)
#pragma unroll
    for (int pd = 0; pd < 2; ++pd)
      acur[t][pd] = *(const bf16x8*)(Wb +
          (size_t)(32 * w + 16 * t + 128 * pd + cl) * 32 + q * 8);

  __syncthreads();
  if constexpr (HASPOOL) {
    // bias prologue: thread == stacked row m (0..127 = Wn, 128..255 = D)
    float s0 = 0.f, s1 = 0.f, s2 = 0.f;
#pragma unroll 16
    for (int c = 0; c < 128; ++c) {
      float x = Wt[c * 256 + tid];
      s0 = fmaf(x, spool[c * 3 + 0], s0);
      s1 = fmaf(x, spool[c * 3 + 1], s1);
      s2 = fmaf(x, spool[c * 3 + 2], s2);
    }
    sb[tid * 3 + 0] = s0;
    sb[tid * 3 + 1] = s1;
    sb[tid * 3 + 2] = s2;
    __syncthreads();
  }

  f32x4 acc[2][2][3] = {};  // [t][pd][v]

#pragma unroll
  for (int ks = 0; ks < KS; ++ks) {
    if (ks + 1 < KS) {
#pragma unroll
      for (int t = 0; t < 2; ++t)
#pragma unroll
        for (int pd = 0; pd < 2; ++pd)
          anxt[t][pd] = *(const bf16x8*)(Wb +
              (size_t)(32 * w + 16 * t + 128 * pd + cl) * 32 + q * 8 +
              (ks + 1) * 8192);
    }
    bf16x8 bb[3];
#pragma unroll
    for (int v = 0; v < 3; ++v)
      bb[v] = *(const bf16x8*)(xt + (v * 16 + cl) * LDR + ks * 32 + q * 8);
#pragma unroll
    for (int t = 0; t < 2; ++t)
#pragma unroll
      for (int pd = 0; pd < 2; ++pd)
#pragma unroll
        for (int v = 0; v < 3; ++v)
          acc[t][pd][v] = __builtin_amdgcn_mfma_f32_16x16x32_bf16(
              acur[t][pd], bb[v], acc[t][pd][v], 0, 0, 0);
#pragma unroll
    for (int t = 0; t < 2; ++t)
#pragma unroll
      for (int pd = 0; pd < 2; ++pd)
        acur[t][pd] = anxt[t][pd];
  }
  __syncthreads();  // X-tile dead; buffer becomes the fp32 out-tile

#pragma unroll
  for (int t = 0; t < 2; ++t) {
    float res[3][4];
#pragma unroll
    for (int r = 0; r < 4; ++r) {
      int o = 32 * w + 16 * t + 4 * q + r;
      float pv[3], dvv[3];
#pragma unroll
      for (int v = 0; v < 3; ++v) {
        pv[v] = acc[t][0][v][r] + (HASPOOL ? sb[o * 3 + v] : 0.f);
        dvv[v] = acc[t][1][v][r] + (HASPOOL ? sb[(128 + o) * 3 + v] : 0.f);
      }
      float dot = fmaf(pv[0], dvv[0], fmaf(pv[1], dvv[1], pv[2] * dvv[2]));
      float dns = fmaf(dvv[0], dvv[0], fmaf(dvv[1], dvv[1], dvv[2] * dvv[2]));
      float f = (dot < 0.f) ? dot / (dns + 1e-6f) : 0.f;
#pragma unroll
      for (int v = 0; v < 3; ++v) res[v][r] = pv[v] - f * dvv[v];
    }
    int o0 = 32 * w + 16 * t + 4 * q;
#pragma unroll
    for (int v = 0; v < 3; ++v) {
      f32x4 rv = {res[v][0], res[v][1], res[v][2], res[v][3]};
      *(f32x4*)(ot + (v * 16 + cl) * LDO + o0) = rv;
    }
  }
  __syncthreads();

  int shadow = (nt & 7) * 3072;
  for (int s = tid; s < 384; s += 256) {
    int o = s / 3, v = s % 3;
    float a2 = 0.f;
#pragma unroll
    for (int c = 0; c < 16; ++c) a2 += ot[(v * 16 + c) * LDO + o];
    if (LAST) atomicAdd(outs + shadow + b * 384 + s, a2);
    else      atomicAdd(pool + shadow + b * 384 + s, a2);
  }

  if constexpr (!LAST) {
    // All pool-reduce reads of ot must complete before the in-place repack.
    __syncthreads();
    for (int s = tid; s < 1536; s += 256) {
      int pix = s >> 5, c4 = s & 31;
      float4 sv = *(float4*)(ot + pix * LDO + c4 * 4);
      uint4 vv;
      vv.x = packhl(sv.x);
      vv.y = packhl(sv.y);
      vv.z = packhl(sv.z);
      vv.w = packhl(sv.w);
      // same 16 bytes we just read: LDO*4 == 264*2 == 528-byte rows
      *(uint4*)(xt + pix * 264 + c4 * 8) = vv;
    }
  }
}

// ---------------------------------------------------------------------------
// FUSED kernel: layer1 -> barrier -> layer2 -> barrier -> layer3 -> barrier
// -> merge.  The 48-pixel activation tile never leaves LDS; only the rank-1
// pooled-mean shadows cross the barriers.  Plain launch => graph-capturable.
// ---------------------------------------------------------------------------
__global__ __launch_bounds__(256, 4) void vnt_stack_kernel(
    float* __restrict__ ws, float* __restrict__ out) {
  __shared__ __align__(16) char smem[48 * 132 * 4];  // 25344 B, dual-purpose
  __shared__ float sb[768];
  __shared__ float spool[384];
  int tid = threadIdx.x;
  int bid = blockIdx.x;
  int b = bid >> 7;
  int nt = bid & 127;
  int p0 = nt * 48;
  unsigned short* xt = (unsigned short*)smem;
  unsigned int* bar = (unsigned int*)(ws + OBAR);

  // layer1: K2=128, stage from global Xp0, pack result into LDS
  vnt_layer_body<128, false, false, true>(
      xt, sb, spool,
      (const unsigned short*)(ws + OXP0), (const unsigned short*)(ws + OWB1),
      nullptr, nullptr, ws + OPS1, nullptr, b, nt, p0, tid);
  grid_barrier(bar + 0);  // ps1 shadows complete

  // layer2: K2=256, tile already in LDS, bias from ps1 + WT2
  vnt_layer_body<256, true, false, false>(
      xt, sb, spool,
      nullptr, (const unsigned short*)(ws + OWB2),
      ws + OPS1, ws + OWT2, ws + OPS2, nullptr, b, nt, p0, tid);
  grid_barrier(bar + 1);  // ps2 shadows complete

  // layer3: K2=256, bias from ps2 + WT3 -> out shadows
  vnt_layer_body<256, true, true, false>(
      xt, sb, spool,
      nullptr, (const unsigned short*)(ws + OWB3),
      ws + OPS2, ws + OWT3, nullptr, ws + OOUTS, b, nt, p0, tid);
  grid_barrier(bar + 2);  // out shadows complete

  // merge: first 12 blocks produce the [B][384] output
  int idx = bid * 256 + tid;
  if (idx < B * 384) {
    const float* outs = ws + OOUTS;
    float s = 0.f;
#pragma unroll
    for (int k = 0; k < 8; ++k) s += outs[k * 3072 + idx];
    out[idx] = s * (1.f / 2048.f);
  }
}

// ---------------------------------------------------------------------------
// launch
// ---------------------------------------------------------------------------
extern "C" void kernel_launch(void* const* d_in, const int* in_sizes, int n_in,
                              void* d_out, int out_size, void* d_ws, size_t ws_size,
                              hipStream_t stream) {
  (void)in_sizes; (void)n_in; (void)out_size; (void)ws_size;
  const float* pc   = (const float*)d_in[0];
  const float* Wpos = (const float*)d_in[1];
  const float* Dpos = (const float*)d_in[2];
  const float* W1   = (const float*)d_in[3];
  const float* D1   = (const float*)d_in[4];
  const float* W2   = (const float*)d_in[5];
  const float* D2   = (const float*)d_in[6];
  const float* W3   = (const float*)d_in[7];
  const float* D3   = (const float*)d_in[8];
  float* out = (float*)d_out;
  float* ws  = (float*)d_ws;

  // fused prep + KNN + edge + pos layer -> Xp0 (+ packed weights, zeroed
  // shadows AND barrier counters)
  knn_edge_kernel<<<dim3(N / QPW, B), 512, 0, stream>>>(
      pc, Wpos, Dpos, W1, D1, W2, D2, W3, D3, ws);

  // fused 3-layer VNT stack + merge (plain launch, software grid barrier)
  vnt_stack_kernel<<<GRID_VNT, 256, 0, stream>>>(ws, out);
}

// Round 3
// 220.078 us; speedup vs baseline: 3.1228x; 3.1228x over previous
//
#include <hip/hip_runtime.h>
#include <hip/hip_bf16.h>
#include <math.h>

// ---------------------------------------------------------------------------
// Problem constants
// ---------------------------------------------------------------------------
constexpr int B = 8;
constexpr int N = 2048;
constexpr int KNN = 20;
constexpr int H = 128;
constexpr int P = 3 * N;  // 6144 pixels per batch
constexpr int QPW = 8;    // queries (waves) per knn_edge block

// ws layout (float offsets)
constexpr int OWT2   = 8448;      // W2/D2 second-half TRANSPOSED [c<128][m<256] (32768)
constexpr int OWT3   = 41216;     // W3/D3 second-half transposed (32768)
constexpr int OPS1   = 73984;     // poolsum1 shadows [8][B][128][3] = 24576
constexpr int OPS2   = 98560;     // poolsum2 shadows = 24576
constexpr int OOUTS  = 123136;    // out shadows [8][B][384] = 24576
constexpr int OBAR   = 147712;    // grid-barrier counters (16 f reserved)
constexpr int OWB1   = 160000;    // Wbig1 bf16 hi/lo, FRAGMENT-MAJOR [ks][256][32h] (16384 f)
constexpr int OWB2   = 176384;    // Wbig2 fragment-major (32768 f)
constexpr int OWB3   = 209152;    // Wbig3 fragment-major (32768 f)
constexpr int OXP0   = 569600;    // Xp0 bf16 [b][P][128] (3145728 f-equiv)

constexpr int ZERO_BASE = OPS1;   // zeroed region = ps1+ps2+outs+barriers
constexpr int ZERO_CNT  = 73744;  // 73728 shadows + 16 barrier counters

constexpr int GRID_VNT  = 1024;   // 4 blocks/CU x 256 CU, exactly co-resident

typedef __attribute__((ext_vector_type(8))) short bf16x8;
typedef __attribute__((ext_vector_type(4))) float f32x4;

__device__ __forceinline__ unsigned short f2bf(float x) {
  __hip_bfloat16 h = __float2bfloat16(x);
  return *(unsigned short*)&h;
}
__device__ __forceinline__ float bf2f(unsigned short u) {
  __hip_bfloat16 h;
  *(unsigned short*)&h = u;
  return __bfloat162float(h);
}
// pack x as (hi, lo) bf16 pair in one uint (hi at lower address)
__device__ __forceinline__ unsigned int packhl(float x) {
  unsigned short hi = f2bf(x);
  float lo = x - bf2f(hi);
  unsigned short ls = f2bf(lo);
  return (unsigned)hi | ((unsigned)ls << 16);
}

// coherent-point read (no cache-maintenance instructions)
__device__ __forceinline__ float cohload(const float* p) {
  return __hip_atomic_load(p, __ATOMIC_RELAXED, __HIP_MEMORY_SCOPE_AGENT);
}

// ---------------------------------------------------------------------------
// Wave-wide bitonic sort of 64 u64 keys, descending (larger key = better).
// Key = ord(value)<<32 | ~index  ==>  value desc, ties -> smaller index.
// ---------------------------------------------------------------------------
__device__ __forceinline__ void wave_sort_key(unsigned long long& k, int lane) {
#pragma unroll
  for (int kk = 2; kk <= 64; kk <<= 1) {
#pragma unroll
    for (int j = kk >> 1; j > 0; j >>= 1) {
      unsigned long long pk =
          (unsigned long long)__shfl_xor((long long)k, j);
      bool iam_lower   = (lane & j) == 0;
      bool dir_desc    = (lane & kk) == 0;
      bool p_better    = pk > k;
      bool want_better = (dir_desc == iam_lower);
      k = (p_better == want_better) ? pk : k;
    }
  }
}

// ---------------------------------------------------------------------------
// K2 (FUSED): prep + exact top-20 KNN + edge + pos layer + mean-k -> Xp0.
// (unchanged from the verified 168 us version)
// ---------------------------------------------------------------------------
__global__ __launch_bounds__(512, 8) void knn_edge_kernel(
    const float* __restrict__ pc, const float* __restrict__ Wpos,
    const float* __restrict__ Dp,
    const float* __restrict__ W1, const float* __restrict__ D1,
    const float* __restrict__ W2, const float* __restrict__ D2,
    const float* __restrict__ W3, const float* __restrict__ D3,
    float* __restrict__ ws) {
  __shared__ float4 spt[N];                       // 32 KB (2x,2y,2z,xx)
  __shared__ __align__(16) unsigned char sphase[QPW][640];   // 5 KB
  int tid = threadIdx.x;
  int b = blockIdx.y;
  int bid = blockIdx.y * gridDim.x + blockIdx.x;  // 0..2047
  int wv = tid >> 6, lane = tid & 63;
  unsigned short* Xp0 = (unsigned short*)(ws + OXP0);
  unsigned short* sbufw = (unsigned short*)sphase[wv];
  float4* erw = (float4*)sphase[wv];

  // hoisted edge-phase weight loads (latency hidden under distance pass)
  int o = lane;
  float w0 = Wpos[o * 3 + 0], w1 = Wpos[o * 3 + 1], w2 = Wpos[o * 3 + 2];
  float e0 = Dp[o * 3 + 0], e1 = Dp[o * 3 + 1], e2 = Dp[o * 3 + 2];

  // ---- folded prep: distributed shadow+barrier zeroing (1 store/thread) ---
  {
    int zi = bid * 512 + tid;
    if (zi < ZERO_CNT) ws[ZERO_BASE + zi] = 0.f;
  }
  // ---- folded prep: 768 weight rows over blocks 0..95 (one wave/row) -----
  if (bid < 96) {
    int rr = bid * 8 + wv;  // 0..767
    const float* src;
    float* tdst = nullptr;
    unsigned int* pdst;   // base of fragment-major region + m*16
    int C, Cpack;
    bool norm;
    if (rr < 128)      { src = W1 + rr * 64;            C = 64;  Cpack = 64;  norm = true;
                         pdst = (unsigned int*)(ws + OWB1) + rr * 16; }
    else if (rr < 256) { int m = rr - 128; src = D1 + m * 64;  C = 64;  Cpack = 64;  norm = false;
                         pdst = (unsigned int*)(ws + OWB1) + (m + 128) * 16; }
    else if (rr < 384) { int m = rr - 256; src = W2 + m * 256; C = 256; Cpack = 128; norm = true;
                         pdst = (unsigned int*)(ws + OWB2) + m * 16; tdst = ws + OWT2 + m; }
    else if (rr < 512) { int m = rr - 384; src = D2 + m * 256; C = 256; Cpack = 128; norm = false;
                         pdst = (unsigned int*)(ws + OWB2) + (m + 128) * 16; tdst = ws + OWT2 + 128 + m; }
    else if (rr < 640) { int m = rr - 512; src = W3 + m * 256; C = 256; Cpack = 128; norm = true;
                         pdst = (unsigned int*)(ws + OWB3) + m * 16; tdst = ws + OWT3 + m; }
    else               { int m = rr - 640; src = D3 + m * 256; C = 256; Cpack = 128; norm = false;
                         pdst = (unsigned int*)(ws + OWB3) + (m + 128) * 16; tdst = ws + OWT3 + 128 + m; }
    float s = 1.f;
    if (norm) {
      float a = 0.f;
      for (int i = lane; i < C; i += 64) a += src[i];
#pragma unroll
      for (int off = 32; off > 0; off >>= 1) a += __shfl_xor(a, off);
      s = a;
    }
    for (int i = lane; i < C; i += 64) {
      float val = src[i] / s;  // exact when s==1
      if (i < Cpack) pdst[(i >> 4) * 4096 + (i & 15)] = packhl(val);
      if (tdst && i >= 128) tdst[(i - 128) * 256] = val;
    }
  }

  // ---- stage point cloud ---------------------------------------------------
  const float* pcb = pc + (size_t)b * N * 3;
  for (int i = tid; i < N; i += 512) {
    float x = pcb[i * 3 + 0], y = pcb[i * 3 + 1], z = pcb[i * 3 + 2];
    float xx = __fadd_rn(__fadd_rn(__fmul_rn(x, x), __fmul_rn(y, y)), __fmul_rn(z, z));
    spt[i] = make_float4(2.f * x, 2.f * y, 2.f * z, xx);
  }
  __syncthreads();
  int q = blockIdx.x * QPW + wv;
  float4 qp = spt[q];
  float qx = 0.5f * qp.x, qy = 0.5f * qp.y, qz = 0.5f * qp.z, qxx = qp.w;

  float dv[32];
  float lmax = -INFINITY;
#pragma unroll
  for (int i = 0; i < 32; ++i) {
    float4 m = spt[i * 64 + lane];
    float A = __fadd_rn(__fadd_rn(__fmul_rn(m.x, qx), __fmul_rn(m.y, qy)),
                        __fmul_rn(m.z, qz));
    float d = __fsub_rn(__fsub_rn(A, qxx), m.w);
    dv[i] = d;
    lmax = fmaxf(lmax, d);
  }

  // value-only bitonic sort (descending) of the 64 lane-maxes; take #19
  float sv = lmax;
#pragma unroll
  for (int k = 2; k <= 64; k <<= 1) {
#pragma unroll
    for (int j = k >> 1; j > 0; j >>= 1) {
      float pv = __shfl_xor(sv, j);
      bool keep_max = ((lane & k) == 0) == ((lane & j) == 0);
      sv = keep_max ? fmaxf(sv, pv) : fminf(sv, pv);
    }
  }
  float tval = __shfl(sv, 19);  // 20th-largest lane-max <= V20 (provable)

  // registerized compact: per-lane survivor mask + shfl prefix scan
  unsigned msk = 0u;
#pragma unroll
  for (int i = 0; i < 32; ++i) msk |= (dv[i] >= tval) ? (1u << i) : 0u;
  int cnt = __popc(msk);
  int scan = cnt;
#pragma unroll
  for (int off = 1; off < 64; off <<= 1) {
    int t = __shfl_up(scan, off);
    scan += (lane >= off) ? t : 0;
  }
  int S = __shfl(scan, 63);
  int pos = scan - cnt;  // exclusive prefix
  unsigned mm = msk;
  while (mm) {
    int i = __ffs(mm) - 1;
    mm &= mm - 1;
    if (pos < 192) sbufw[pos] = (unsigned short)(i * 64 + lane);
    ++pos;
  }

  auto distOf = [&](int m) -> float {
    float4 mp = spt[m];
    float A = __fadd_rn(__fadd_rn(__fmul_rn(mp.x, qx), __fmul_rn(mp.y, qy)),
                        __fmul_rn(mp.z, qz));
    return __fsub_rn(__fsub_rn(A, qxx), mp.w);
  };
  auto mkkey = [&](int m) -> unsigned long long {
    float d = distOf(m);
    unsigned u = __float_as_uint(d);
    u ^= (u >> 31) ? 0xFFFFFFFFu : 0x80000000u;
    return ((unsigned long long)u << 32) | (unsigned)(~m);
  };

  unsigned long long key = 0ULL;  // padding key: below every real key
  if (S <= 64) {
    if (lane < S) key = mkkey(sbufw[lane]);
    wave_sort_key(key, lane);
  } else if (S <= 192) {
    int p2 = 0;
    while (p2 < S) {
      if (lane >= KNN) {
        int t = p2 + lane - KNN;
        key = (t < S) ? mkkey(sbufw[t]) : 0ULL;
      }
      wave_sort_key(key, lane);
      p2 += 64 - KNN;
    }
  } else {
    int p2 = 0;
    while (p2 < N) {
      if (lane >= KNN) {
        int t = p2 + lane - KNN;
        key = (t < N) ? mkkey(t) : 0ULL;
      }
      wave_sort_key(key, lane);
      p2 += 64 - KNN;
    }
  }
  int cm = ~((unsigned)key);  // valid in lanes 0..19

  // ---- edge geometry precompute: lane k<20 computes e/r once --------------
  if (lane < KNN) {
    float4 t = spt[cm];
    float nx = 0.5f * t.x, ny = 0.5f * t.y, nz = 0.5f * t.z;
    float ex = nx - qx, ey = ny - qy, ez = nz - qz;
    float rx = ny * qz - nz * qy;
    float ry = nz * qx - nx * qz;
    float rz = nx * qy - ny * qx;
    erw[2 * lane + 0] = make_float4(ex, ey, ez, 0.f);
    erw[2 * lane + 1] = make_float4(rx, ry, rz, 0.f);
  }

  // ---- edge + pos layer (lane o = channel o) -------------------------------
  {
    float s = (w0 + w2) + w1;
    w0 = w0 / s; w1 = w1 / s; w2 = w2 / s;
  }
  float cx = qx, cy = qy, cz = qz;  // exact raw coords (0.5 * 2x)
  float pcx = w1 * cx, pcy = w1 * cy, pcz = w1 * cz;
  float dcx = e1 * cx, dcy = e1 * cy, dcz = e1 * cz;
  float ax = 0.f, ay = 0.f, az = 0.f;
#pragma unroll 4
  for (int k = 0; k < KNN; ++k) {
    float4 e4 = erw[2 * k + 0];   // broadcast LDS reads
    float4 r4 = erw[2 * k + 1];
    float ex = e4.x, ey = e4.y, ez = e4.z;
    float rx = r4.x, ry = r4.y, rz = r4.z;
    float px = fmaf(w0, ex, fmaf(w2, rx, pcx));
    float py = fmaf(w0, ey, fmaf(w2, ry, pcy));
    float pz = fmaf(w0, ez, fmaf(w2, rz, pcz));
    float dx = fmaf(e0, ex, fmaf(e2, rx, dcx));
    float dy = fmaf(e0, ey, fmaf(e2, ry, dcy));
    float dz = fmaf(e0, ez, fmaf(e2, rz, dcz));
    float dot = fmaf(px, dx, fmaf(py, dy, pz * dz));
    float dns = fmaf(dx, dx, fmaf(dy, dy, dz * dz)) + 1e-6f;
    float r0 = __builtin_amdgcn_rcpf(dns);
    r0 = r0 * fmaf(-dns, r0, 2.0f);          // 1 Newton step
    float f = (dot < 0.f) ? dot * r0 : 0.f;
    ax = fmaf(-f, dx, px) + ax;
    ay = fmaf(-f, dy, py) + ay;
    az = fmaf(-f, dz, pz) + az;
  }
  int pbase = ((q >> 4) * 48) + (q & 15);
  unsigned short* dst = Xp0 + ((size_t)b * P + pbase) * 128 + 2 * o;
  *(unsigned int*)(dst)              = packhl(ax * (1.f / 20.f));
  *(unsigned int*)(dst + 16 * 128)   = packhl(ay * (1.f / 20.f));
  *(unsigned int*)(dst + 32 * 128)   = packhl(az * (1.f / 20.f));
}

// ---------------------------------------------------------------------------
// Software grid barrier — FENCE-FREE.
// All cross-block data is written with device-scope atomicAdd (coherent point,
// m20) and read with relaxed agent-scope atomic loads; no wbl2/inv needed.
// __syncthreads() drains vmcnt(0) per wave, so every atomicAdd of this block
// is complete at the coherent point before tid0 signals arrival.
// Safe (no deadlock) because all GRID_VNT blocks are co-resident by
// construction: VGPR<=128, LDS 30208 B -> exactly 4 blocks/CU x 256 CU.
// ---------------------------------------------------------------------------
__device__ __forceinline__ void grid_barrier(unsigned int* cnt) {
  __syncthreads();
  if (threadIdx.x == 0) {
    __hip_atomic_fetch_add(cnt, 1u, __ATOMIC_RELAXED, __HIP_MEMORY_SCOPE_AGENT);
    while (__hip_atomic_load(cnt, __ATOMIC_RELAXED,
                             __HIP_MEMORY_SCOPE_AGENT) < (unsigned)GRID_VNT) {
      __builtin_amdgcn_s_sleep(2);
    }
  }
  __syncthreads();
}

// ---------------------------------------------------------------------------
// Shared VNT layer body.
// GSRC=true : stage the X tile [48][K2] from global Xp into LDS.
// GSRC=false: the X tile is ALREADY in LDS (packed in place by the previous
//             layer, byte-identical to what staging would have produced).
// The in-place repack works because LDO*4 bytes == (256+8)*2 bytes == 528.
// Pool-shadow reads use coherent-point loads (written by atomicAdd pre-barrier).
// ---------------------------------------------------------------------------
template <int K2, bool HASPOOL, bool LAST, bool GSRC>
__device__ __forceinline__ void vnt_layer_body(
    unsigned short* xt, float* sb, float* spool,
    const unsigned short* __restrict__ Xp, const unsigned short* __restrict__ Wb,
    const float* __restrict__ ps, const float* __restrict__ Wt,
    float* __restrict__ pool, float* __restrict__ outs,
    int b, int nt, int p0, int tid) {
  constexpr int KS = K2 / 32;
  constexpr int LDR = K2 + 8;   // halves; X-tile row stride
  constexpr int LDO = 132;      // floats; out-tile row stride
  float* ot = (float*)xt;
  int w = tid >> 6, lane = tid & 63;
  int q = lane >> 4, cl = lane & 15;

  if constexpr (GSRC) {
    // stage X tile [48][K2] -> LDS
    for (int ch = tid; ch < 48 * (K2 / 8); ch += 256) {
      int rp = ch / (K2 / 8), cc = ch % (K2 / 8);
      *(uint4*)(xt + rp * LDR + cc * 8) =
          *(const uint4*)(Xp + ((size_t)b * P + p0 + rp) * K2 + cc * 8);
    }
  }
  if constexpr (HASPOOL) {
    // pooled mean (sum of 8 shadow copies, coherent-point reads) -> LDS
    for (int i = tid; i < 384; i += 256) {
      float x = 0.f;
#pragma unroll
      for (int k = 0; k < 8; ++k)
        x += cohload(&ps[k * 3072 + b * 384 + i]);
      spool[i] = x * (1.f / 2048.f);
    }
  }

  // first A-fragments: global, LDS-independent -> issue before the barrier
  bf16x8 acur[2][2], anxt[2][2];
#pragma unroll
  for (int t = 0; t < 2; ++t)
#pragma unroll
    for (int pd = 0; pd < 2; ++pd)
      acur[t][pd] = *(const bf16x8*)(Wb +
          (size_t)(32 * w + 16 * t + 128 * pd + cl) * 32 + q * 8);

  __syncthreads();
  if constexpr (HASPOOL) {
    // bias prologue: thread == stacked row m (0..127 = Wn, 128..255 = D)
    float s0 = 0.f, s1 = 0.f, s2 = 0.f;
#pragma unroll 16
    for (int c = 0; c < 128; ++c) {
      float x = Wt[c * 256 + tid];
      s0 = fmaf(x, spool[c * 3 + 0], s0);
      s1 = fmaf(x, spool[c * 3 + 1], s1);
      s2 = fmaf(x, spool[c * 3 + 2], s2);
    }
    sb[tid * 3 + 0] = s0;
    sb[tid * 3 + 1] = s1;
    sb[tid * 3 + 2] = s2;
    __syncthreads();
  }

  f32x4 acc[2][2][3] = {};  // [t][pd][v]

#pragma unroll
  for (int ks = 0; ks < KS; ++ks) {
    if (ks + 1 < KS) {
#pragma unroll
      for (int t = 0; t < 2; ++t)
#pragma unroll
        for (int pd = 0; pd < 2; ++pd)
          anxt[t][pd] = *(const bf16x8*)(Wb +
              (size_t)(32 * w + 16 * t + 128 * pd + cl) * 32 + q * 8 +
              (ks + 1) * 8192);
    }
    bf16x8 bb[3];
#pragma unroll
    for (int v = 0; v < 3; ++v)
      bb[v] = *(const bf16x8*)(xt + (v * 16 + cl) * LDR + ks * 32 + q * 8);
#pragma unroll
    for (int t = 0; t < 2; ++t)
#pragma unroll
      for (int pd = 0; pd < 2; ++pd)
#pragma unroll
        for (int v = 0; v < 3; ++v)
          acc[t][pd][v] = __builtin_amdgcn_mfma_f32_16x16x32_bf16(
              acur[t][pd], bb[v], acc[t][pd][v], 0, 0, 0);
#pragma unroll
    for (int t = 0; t < 2; ++t)
#pragma unroll
      for (int pd = 0; pd < 2; ++pd)
        acur[t][pd] = anxt[t][pd];
  }
  __syncthreads();  // X-tile dead; buffer becomes the fp32 out-tile

#pragma unroll
  for (int t = 0; t < 2; ++t) {
    float res[3][4];
#pragma unroll
    for (int r = 0; r < 4; ++r) {
      int o = 32 * w + 16 * t + 4 * q + r;
      float pv[3], dvv[3];
#pragma unroll
      for (int v = 0; v < 3; ++v) {
        pv[v] = acc[t][0][v][r] + (HASPOOL ? sb[o * 3 + v] : 0.f);
        dvv[v] = acc[t][1][v][r] + (HASPOOL ? sb[(128 + o) * 3 + v] : 0.f);
      }
      float dot = fmaf(pv[0], dvv[0], fmaf(pv[1], dvv[1], pv[2] * dvv[2]));
      float dns = fmaf(dvv[0], dvv[0], fmaf(dvv[1], dvv[1], dvv[2] * dvv[2]));
      float f = (dot < 0.f) ? dot / (dns + 1e-6f) : 0.f;
#pragma unroll
      for (int v = 0; v < 3; ++v) res[v][r] = pv[v] - f * dvv[v];
    }
    int o0 = 32 * w + 16 * t + 4 * q;
#pragma unroll
    for (int v = 0; v < 3; ++v) {
      f32x4 rv = {res[v][0], res[v][1], res[v][2], res[v][3]};
      *(f32x4*)(ot + (v * 16 + cl) * LDO + o0) = rv;
    }
  }
  __syncthreads();

  int shadow = (nt & 7) * 3072;
  for (int s = tid; s < 384; s += 256) {
    int o = s / 3, v = s % 3;
    float a2 = 0.f;
#pragma unroll
    for (int c = 0; c < 16; ++c) a2 += ot[(v * 16 + c) * LDO + o];
    if (LAST) atomicAdd(outs + shadow + b * 384 + s, a2);
    else      atomicAdd(pool + shadow + b * 384 + s, a2);
  }

  if constexpr (!LAST) {
    // All pool-reduce reads of ot must complete before the in-place repack.
    __syncthreads();
    for (int s = tid; s < 1536; s += 256) {
      int pix = s >> 5, c4 = s & 31;
      float4 sv = *(float4*)(ot + pix * LDO + c4 * 4);
      uint4 vv;
      vv.x = packhl(sv.x);
      vv.y = packhl(sv.y);
      vv.z = packhl(sv.z);
      vv.w = packhl(sv.w);
      // same 16 bytes we just read: LDO*4 == 264*2 == 528-byte rows
      *(uint4*)(xt + pix * 264 + c4 * 8) = vv;
    }
  }
}

// ---------------------------------------------------------------------------
// FUSED kernel: layer1 -> barrier -> layer2 -> barrier -> layer3 ->
// last-block merge.  The 48-pixel activation tile never leaves LDS; only the
// rank-1 pooled-mean shadows cross the barriers.  Plain launch, no fences.
// ---------------------------------------------------------------------------
__global__ __launch_bounds__(256, 4) void vnt_stack_kernel(
    float* __restrict__ ws, float* __restrict__ out) {
  __shared__ __align__(16) char smem[48 * 132 * 4];  // 25344 B, dual-purpose
  __shared__ float sb[768];
  __shared__ float spool[384];
  __shared__ unsigned int last_flag;
  int tid = threadIdx.x;
  int bid = blockIdx.x;
  int b = bid >> 7;
  int nt = bid & 127;
  int p0 = nt * 48;
  unsigned short* xt = (unsigned short*)smem;
  unsigned int* bar = (unsigned int*)(ws + OBAR);

  // layer1: K2=128, stage from global Xp0, pack result into LDS
  vnt_layer_body<128, false, false, true>(
      xt, sb, spool,
      (const unsigned short*)(ws + OXP0), (const unsigned short*)(ws + OWB1),
      nullptr, nullptr, ws + OPS1, nullptr, b, nt, p0, tid);
  grid_barrier(bar + 0);  // ps1 shadows complete

  // layer2: K2=256, tile already in LDS, bias from ps1 + WT2
  vnt_layer_body<256, true, false, false>(
      xt, sb, spool,
      nullptr, (const unsigned short*)(ws + OWB2),
      ws + OPS1, ws + OWT2, ws + OPS2, nullptr, b, nt, p0, tid);
  grid_barrier(bar + 1);  // ps2 shadows complete

  // layer3: K2=256, bias from ps2 + WT3 -> out shadows
  vnt_layer_body<256, true, true, false>(
      xt, sb, spool,
      nullptr, (const unsigned short*)(ws + OWB3),
      ws + OPS2, ws + OWT3, nullptr, ws + OOUTS, b, nt, p0, tid);

  // last-arriving block performs the merge; everyone else just exits.
  __syncthreads();  // drain this block's outs atomicAdds (vmcnt 0)
  if (tid == 0) {
    unsigned old = __hip_atomic_fetch_add(bar + 2, 1u, __ATOMIC_RELAXED,
                                          __HIP_MEMORY_SCOPE_AGENT);
    last_flag = (old == (unsigned)GRID_VNT - 1) ? 1u : 0u;
  }
  __syncthreads();
  if (last_flag) {
    const float* outs = ws + OOUTS;
    for (int idx = tid; idx < B * 384; idx += 256) {
      float s = 0.f;
#pragma unroll
      for (int k = 0; k < 8; ++k) s += cohload(&outs[k * 3072 + idx]);
      out[idx] = s * (1.f / 2048.f);
    }
  }
}

// ---------------------------------------------------------------------------
// launch
// ---------------------------------------------------------------------------
extern "C" void kernel_launch(void* const* d_in, const int* in_sizes, int n_in,
                              void* d_out, int out_size, void* d_ws, size_t ws_size,
                              hipStream_t stream) {
  (void)in_sizes; (void)n_in; (void)out_size; (void)ws_size;
  const float* pc   = (const float*)d_in[0];
  const float* Wpos = (const float*)d_in[1];
  const float* Dpos = (const float*)d_in[2];
  const float* W1   = (const float*)d_in[3];
  const float* D1   = (const float*)d_in[4];
  const float* W2   = (const float*)d_in[5];
  const float* D2   = (const float*)d_in[6];
  const float* W3   = (const float*)d_in[7];
  const float* D3   = (const float*)d_in[8];
  float* out = (float*)d_out;
  float* ws  = (float*)d_ws;

  // fused prep + KNN + edge + pos layer -> Xp0 (+ packed weights, zeroed
  // shadows AND barrier counters)
  knn_edge_kernel<<<dim3(N / QPW, B), 512, 0, stream>>>(
      pc, Wpos, Dpos, W1, D1, W2, D2, W3, D3, ws);

  // fused 3-layer VNT stack + last-block merge (plain launch, fence-free
  // software grid barriers)
  vnt_stack_kernel<<<GRID_VNT, 256, 0, stream>>>(ws, out);
}

// Round 4
// 187.060 us; speedup vs baseline: 3.6740x; 1.1765x over previous
//
#include <hip/hip_runtime.h>
#include <hip/hip_bf16.h>
#include <math.h>

// ---------------------------------------------------------------------------
// Problem constants
// ---------------------------------------------------------------------------
constexpr int B = 8;
constexpr int N = 2048;
constexpr int KNN = 20;
constexpr int H = 128;
constexpr int P = 3 * N;  // 6144 pixels per batch
constexpr int QPW = 8;    // queries (waves) per knn_edge block

// ws layout (float offsets)
constexpr int OWT2   = 8448;      // W2/D2 second-half TRANSPOSED [c<128][m<256] (32768)
constexpr int OWT3   = 41216;     // W3/D3 second-half transposed (32768)
constexpr int OPS1   = 73984;     // poolsum1 shadows [8][B][128][3] = 24576
constexpr int OPS2   = 98560;     // poolsum2 shadows = 24576
constexpr int OOUTS  = 123136;    // out shadows [8][B][384] = 24576
constexpr int OBAR   = 147712;    // barrier counters: [2][8] per-batch (32-f spaced) + merge (1024 f reserved)
constexpr int OWB1   = 160000;    // Wbig1 bf16 hi/lo, FRAGMENT-MAJOR [ks][256][32h] (16384 f)
constexpr int OWB2   = 176384;    // Wbig2 fragment-major (32768 f)
constexpr int OWB3   = 209152;    // Wbig3 fragment-major (32768 f)
constexpr int OXP0   = 569600;    // Xp0 bf16 [b][P][128] (3145728 f-equiv)

constexpr int ZERO_BASE = OPS1;   // zeroed region = ps1+ps2+outs+barriers
constexpr int ZERO_CNT  = 74752;  // 73728 shadows + 1024 barrier words

constexpr int GRID_VNT  = 1024;   // 4 blocks/CU x 256 CU, exactly co-resident
constexpr int BLK_PER_B = 128;    // blocks per batch (per-batch barrier target)

typedef __attribute__((ext_vector_type(8))) short bf16x8;
typedef __attribute__((ext_vector_type(4))) float f32x4;

__device__ __forceinline__ unsigned short f2bf(float x) {
  __hip_bfloat16 h = __float2bfloat16(x);
  return *(unsigned short*)&h;
}
__device__ __forceinline__ float bf2f(unsigned short u) {
  __hip_bfloat16 h;
  *(unsigned short*)&h = u;
  return __bfloat162float(h);
}
// pack x as (hi, lo) bf16 pair in one uint (hi at lower address)
__device__ __forceinline__ unsigned int packhl(float x) {
  unsigned short hi = f2bf(x);
  float lo = x - bf2f(hi);
  unsigned short ls = f2bf(lo);
  return (unsigned)hi | ((unsigned)ls << 16);
}

// coherent-point read (no cache-maintenance instructions)
__device__ __forceinline__ float cohload(const float* p) {
  return __hip_atomic_load(p, __ATOMIC_RELAXED, __HIP_MEMORY_SCOPE_AGENT);
}

// ---------------------------------------------------------------------------
// Wave-wide bitonic sort of 64 u64 keys, descending (larger key = better).
// Key = ord(value)<<32 | ~index  ==>  value desc, ties -> smaller index.
// ---------------------------------------------------------------------------
__device__ __forceinline__ void wave_sort_key(unsigned long long& k, int lane) {
#pragma unroll
  for (int kk = 2; kk <= 64; kk <<= 1) {
#pragma unroll
    for (int j = kk >> 1; j > 0; j >>= 1) {
      unsigned long long pk =
          (unsigned long long)__shfl_xor((long long)k, j);
      bool iam_lower   = (lane & j) == 0;
      bool dir_desc    = (lane & kk) == 0;
      bool p_better    = pk > k;
      bool want_better = (dir_desc == iam_lower);
      k = (p_better == want_better) ? pk : k;
    }
  }
}

// ---------------------------------------------------------------------------
// K2 (FUSED): prep + exact top-20 KNN + edge + pos layer + mean-k -> Xp0.
// (unchanged from the verified version; zero-region widened to 74752)
// ---------------------------------------------------------------------------
__global__ __launch_bounds__(512, 8) void knn_edge_kernel(
    const float* __restrict__ pc, const float* __restrict__ Wpos,
    const float* __restrict__ Dp,
    const float* __restrict__ W1, const float* __restrict__ D1,
    const float* __restrict__ W2, const float* __restrict__ D2,
    const float* __restrict__ W3, const float* __restrict__ D3,
    float* __restrict__ ws) {
  __shared__ float4 spt[N];                       // 32 KB (2x,2y,2z,xx)
  __shared__ __align__(16) unsigned char sphase[QPW][640];   // 5 KB
  int tid = threadIdx.x;
  int b = blockIdx.y;
  int bid = blockIdx.y * gridDim.x + blockIdx.x;  // 0..2047
  int wv = tid >> 6, lane = tid & 63;
  unsigned short* Xp0 = (unsigned short*)(ws + OXP0);
  unsigned short* sbufw = (unsigned short*)sphase[wv];
  float4* erw = (float4*)sphase[wv];

  // hoisted edge-phase weight loads (latency hidden under distance pass)
  int o = lane;
  float w0 = Wpos[o * 3 + 0], w1 = Wpos[o * 3 + 1], w2 = Wpos[o * 3 + 2];
  float e0 = Dp[o * 3 + 0], e1 = Dp[o * 3 + 1], e2 = Dp[o * 3 + 2];

  // ---- folded prep: distributed shadow+barrier zeroing (1 store/thread) ---
  {
    int zi = bid * 512 + tid;
    if (zi < ZERO_CNT) ws[ZERO_BASE + zi] = 0.f;
  }
  // ---- folded prep: 768 weight rows over blocks 0..95 (one wave/row) -----
  if (bid < 96) {
    int rr = bid * 8 + wv;  // 0..767
    const float* src;
    float* tdst = nullptr;
    unsigned int* pdst;   // base of fragment-major region + m*16
    int C, Cpack;
    bool norm;
    if (rr < 128)      { src = W1 + rr * 64;            C = 64;  Cpack = 64;  norm = true;
                         pdst = (unsigned int*)(ws + OWB1) + rr * 16; }
    else if (rr < 256) { int m = rr - 128; src = D1 + m * 64;  C = 64;  Cpack = 64;  norm = false;
                         pdst = (unsigned int*)(ws + OWB1) + (m + 128) * 16; }
    else if (rr < 384) { int m = rr - 256; src = W2 + m * 256; C = 256; Cpack = 128; norm = true;
                         pdst = (unsigned int*)(ws + OWB2) + m * 16; tdst = ws + OWT2 + m; }
    else if (rr < 512) { int m = rr - 384; src = D2 + m * 256; C = 256; Cpack = 128; norm = false;
                         pdst = (unsigned int*)(ws + OWB2) + (m + 128) * 16; tdst = ws + OWT2 + 128 + m; }
    else if (rr < 640) { int m = rr - 512; src = W3 + m * 256; C = 256; Cpack = 128; norm = true;
                         pdst = (unsigned int*)(ws + OWB3) + m * 16; tdst = ws + OWT3 + m; }
    else               { int m = rr - 640; src = D3 + m * 256; C = 256; Cpack = 128; norm = false;
                         pdst = (unsigned int*)(ws + OWB3) + (m + 128) * 16; tdst = ws + OWT3 + 128 + m; }
    float s = 1.f;
    if (norm) {
      float a = 0.f;
      for (int i = lane; i < C; i += 64) a += src[i];
#pragma unroll
      for (int off = 32; off > 0; off >>= 1) a += __shfl_xor(a, off);
      s = a;
    }
    for (int i = lane; i < C; i += 64) {
      float val = src[i] / s;  // exact when s==1
      if (i < Cpack) pdst[(i >> 4) * 4096 + (i & 15)] = packhl(val);
      if (tdst && i >= 128) tdst[(i - 128) * 256] = val;
    }
  }

  // ---- stage point cloud ---------------------------------------------------
  const float* pcb = pc + (size_t)b * N * 3;
  for (int i = tid; i < N; i += 512) {
    float x = pcb[i * 3 + 0], y = pcb[i * 3 + 1], z = pcb[i * 3 + 2];
    float xx = __fadd_rn(__fadd_rn(__fmul_rn(x, x), __fmul_rn(y, y)), __fmul_rn(z, z));
    spt[i] = make_float4(2.f * x, 2.f * y, 2.f * z, xx);
  }
  __syncthreads();
  int q = blockIdx.x * QPW + wv;
  float4 qp = spt[q];
  float qx = 0.5f * qp.x, qy = 0.5f * qp.y, qz = 0.5f * qp.z, qxx = qp.w;

  float dv[32];
  float lmax = -INFINITY;
#pragma unroll
  for (int i = 0; i < 32; ++i) {
    float4 m = spt[i * 64 + lane];
    float A = __fadd_rn(__fadd_rn(__fmul_rn(m.x, qx), __fmul_rn(m.y, qy)),
                        __fmul_rn(m.z, qz));
    float d = __fsub_rn(__fsub_rn(A, qxx), m.w);
    dv[i] = d;
    lmax = fmaxf(lmax, d);
  }

  // value-only bitonic sort (descending) of the 64 lane-maxes; take #19
  float sv = lmax;
#pragma unroll
  for (int k = 2; k <= 64; k <<= 1) {
#pragma unroll
    for (int j = k >> 1; j > 0; j >>= 1) {
      float pv = __shfl_xor(sv, j);
      bool keep_max = ((lane & k) == 0) == ((lane & j) == 0);
      sv = keep_max ? fmaxf(sv, pv) : fminf(sv, pv);
    }
  }
  float tval = __shfl(sv, 19);  // 20th-largest lane-max <= V20 (provable)

  // registerized compact: per-lane survivor mask + shfl prefix scan
  unsigned msk = 0u;
#pragma unroll
  for (int i = 0; i < 32; ++i) msk |= (dv[i] >= tval) ? (1u << i) : 0u;
  int cnt = __popc(msk);
  int scan = cnt;
#pragma unroll
  for (int off = 1; off < 64; off <<= 1) {
    int t = __shfl_up(scan, off);
    scan += (lane >= off) ? t : 0;
  }
  int S = __shfl(scan, 63);
  int pos = scan - cnt;  // exclusive prefix
  unsigned mm = msk;
  while (mm) {
    int i = __ffs(mm) - 1;
    mm &= mm - 1;
    if (pos < 192) sbufw[pos] = (unsigned short)(i * 64 + lane);
    ++pos;
  }

  auto distOf = [&](int m) -> float {
    float4 mp = spt[m];
    float A = __fadd_rn(__fadd_rn(__fmul_rn(mp.x, qx), __fmul_rn(mp.y, qy)),
                        __fmul_rn(mp.z, qz));
    return __fsub_rn(__fsub_rn(A, qxx), mp.w);
  };
  auto mkkey = [&](int m) -> unsigned long long {
    float d = distOf(m);
    unsigned u = __float_as_uint(d);
    u ^= (u >> 31) ? 0xFFFFFFFFu : 0x80000000u;
    return ((unsigned long long)u << 32) | (unsigned)(~m);
  };

  unsigned long long key = 0ULL;  // padding key: below every real key
  if (S <= 64) {
    if (lane < S) key = mkkey(sbufw[lane]);
    wave_sort_key(key, lane);
  } else if (S <= 192) {
    int p2 = 0;
    while (p2 < S) {
      if (lane >= KNN) {
        int t = p2 + lane - KNN;
        key = (t < S) ? mkkey(sbufw[t]) : 0ULL;
      }
      wave_sort_key(key, lane);
      p2 += 64 - KNN;
    }
  } else {
    int p2 = 0;
    while (p2 < N) {
      if (lane >= KNN) {
        int t = p2 + lane - KNN;
        key = (t < N) ? mkkey(t) : 0ULL;
      }
      wave_sort_key(key, lane);
      p2 += 64 - KNN;
    }
  }
  int cm = ~((unsigned)key);  // valid in lanes 0..19

  // ---- edge geometry precompute: lane k<20 computes e/r once --------------
  if (lane < KNN) {
    float4 t = spt[cm];
    float nx = 0.5f * t.x, ny = 0.5f * t.y, nz = 0.5f * t.z;
    float ex = nx - qx, ey = ny - qy, ez = nz - qz;
    float rx = ny * qz - nz * qy;
    float ry = nz * qx - nx * qz;
    float rz = nx * qy - ny * qx;
    erw[2 * lane + 0] = make_float4(ex, ey, ez, 0.f);
    erw[2 * lane + 1] = make_float4(rx, ry, rz, 0.f);
  }

  // ---- edge + pos layer (lane o = channel o) -------------------------------
  {
    float s = (w0 + w2) + w1;
    w0 = w0 / s; w1 = w1 / s; w2 = w2 / s;
  }
  float cx = qx, cy = qy, cz = qz;  // exact raw coords (0.5 * 2x)
  float pcx = w1 * cx, pcy = w1 * cy, pcz = w1 * cz;
  float dcx = e1 * cx, dcy = e1 * cy, dcz = e1 * cz;
  float ax = 0.f, ay = 0.f, az = 0.f;
#pragma unroll 4
  for (int k = 0; k < KNN; ++k) {
    float4 e4 = erw[2 * k + 0];   // broadcast LDS reads
    float4 r4 = erw[2 * k + 1];
    float ex = e4.x, ey = e4.y, ez = e4.z;
    float rx = r4.x, ry = r4.y, rz = r4.z;
    float px = fmaf(w0, ex, fmaf(w2, rx, pcx));
    float py = fmaf(w0, ey, fmaf(w2, ry, pcy));
    float pz = fmaf(w0, ez, fmaf(w2, rz, pcz));
    float dx = fmaf(e0, ex, fmaf(e2, rx, dcx));
    float dy = fmaf(e0, ey, fmaf(e2, ry, dcy));
    float dz = fmaf(e0, ez, fmaf(e2, rz, dcz));
    float dot = fmaf(px, dx, fmaf(py, dy, pz * dz));
    float dns = fmaf(dx, dx, fmaf(dy, dy, dz * dz)) + 1e-6f;
    float r0 = __builtin_amdgcn_rcpf(dns);
    r0 = r0 * fmaf(-dns, r0, 2.0f);          // 1 Newton step
    float f = (dot < 0.f) ? dot * r0 : 0.f;
    ax = fmaf(-f, dx, px) + ax;
    ay = fmaf(-f, dy, py) + ay;
    az = fmaf(-f, dz, pz) + az;
  }
  int pbase = ((q >> 4) * 48) + (q & 15);
  unsigned short* dst = Xp0 + ((size_t)b * P + pbase) * 128 + 2 * o;
  *(unsigned int*)(dst)              = packhl(ax * (1.f / 20.f));
  *(unsigned int*)(dst + 16 * 128)   = packhl(ay * (1.f / 20.f));
  *(unsigned int*)(dst + 32 * 128)   = packhl(az * (1.f / 20.f));
}

// ---------------------------------------------------------------------------
// Shared VNT layer body — arrive/wait split.
//
// The per-batch pool dependency gates ONLY the bias epilogue, not the MFMA
// K-loop.  So: run the K-loop first, THEN wait on the per-batch counter
// (expected already satisfied -> near-zero spin), then bias + epilogue.
// Each block ARRIVES (fetch_add on the per-batch counter for the next layer)
// immediately after its pool-adds, before doing its LDS repack.
//
// GSRC=true : stage the X tile [48][K2] from global Xp into LDS.
// GSRC=false: tile already in LDS (repacked in place by the previous layer).
// In-place repack valid because LDO*4 bytes == (256+8)*2 bytes == 528.
// All cross-block data is written by device-scope atomicAdd (coherent point)
// and read with relaxed agent-scope loads; __syncthreads drains vmcnt before
// tid0 signals.  No cache-maintenance instructions anywhere.
// ---------------------------------------------------------------------------
template <int K2, bool HASPOOL, bool LAST, bool GSRC>
__device__ __forceinline__ void vnt_layer_body(
    unsigned short* xt, float* sb, float* spool,
    const unsigned short* __restrict__ Xp, const unsigned short* __restrict__ Wb,
    const float* __restrict__ ps, const float* __restrict__ Wt,
    float* __restrict__ pool, float* __restrict__ outs,
    unsigned int* wait_cnt, unsigned int* arrive_cnt,
    int b, int nt, int p0, int tid) {
  constexpr int KS = K2 / 32;
  constexpr int LDR = K2 + 8;   // halves; X-tile row stride
  constexpr int LDO = 132;      // floats; out-tile row stride
  float* ot = (float*)xt;
  int w = tid >> 6, lane = tid & 63;
  int q = lane >> 4, cl = lane & 15;

  if constexpr (GSRC) {
    // stage X tile [48][K2] -> LDS
    for (int ch = tid; ch < 48 * (K2 / 8); ch += 256) {
      int rp = ch / (K2 / 8), cc = ch % (K2 / 8);
      *(uint4*)(xt + rp * LDR + cc * 8) =
          *(const uint4*)(Xp + ((size_t)b * P + p0 + rp) * K2 + cc * 8);
    }
  }

  // first A-fragments: global, LDS-independent -> issue before the barrier
  bf16x8 acur[2][2], anxt[2][2];
#pragma unroll
  for (int t = 0; t < 2; ++t)
#pragma unroll
    for (int pd = 0; pd < 2; ++pd)
      acur[t][pd] = *(const bf16x8*)(Wb +
          (size_t)(32 * w + 16 * t + 128 * pd + cl) * 32 + q * 8);

  __syncthreads();  // staging (GSRC) or previous repack visible to all waves

  f32x4 acc[2][2][3] = {};  // [t][pd][v]

#pragma unroll
  for (int ks = 0; ks < KS; ++ks) {
    if (ks + 1 < KS) {
#pragma unroll
      for (int t = 0; t < 2; ++t)
#pragma unroll
        for (int pd = 0; pd < 2; ++pd)
          anxt[t][pd] = *(const bf16x8*)(Wb +
              (size_t)(32 * w + 16 * t + 128 * pd + cl) * 32 + q * 8 +
              (ks + 1) * 8192);
    }
    bf16x8 bb[3];
#pragma unroll
    for (int v = 0; v < 3; ++v)
      bb[v] = *(const bf16x8*)(xt + (v * 16 + cl) * LDR + ks * 32 + q * 8);
#pragma unroll
    for (int t = 0; t < 2; ++t)
#pragma unroll
      for (int pd = 0; pd < 2; ++pd)
#pragma unroll
        for (int v = 0; v < 3; ++v)
          acc[t][pd][v] = __builtin_amdgcn_mfma_f32_16x16x32_bf16(
              acur[t][pd], bb[v], acc[t][pd][v], 0, 0, 0);
#pragma unroll
    for (int t = 0; t < 2; ++t)
#pragma unroll
      for (int pd = 0; pd < 2; ++pd)
        acur[t][pd] = anxt[t][pd];
  }

  // per-batch wait: expected near-zero spin (all batch peers arrived while
  // we ran the K-loop).  tid0 spins; others park at the barrier.
  if constexpr (HASPOOL) {
    if (tid == 0) {
      while (__hip_atomic_load(wait_cnt, __ATOMIC_RELAXED,
                               __HIP_MEMORY_SCOPE_AGENT) < (unsigned)BLK_PER_B) {
        __builtin_amdgcn_s_sleep(4);
      }
    }
  }
  __syncthreads();  // X-tile reads done (ot reuse OK) + wait satisfied

  if constexpr (HASPOOL) {
    // pooled mean (sum of 8 shadow copies, coherent-point reads) -> LDS
    for (int i = tid; i < 384; i += 256) {
      float x = 0.f;
#pragma unroll
      for (int k = 0; k < 8; ++k)
        x += cohload(&ps[k * 3072 + b * 384 + i]);
      spool[i] = x * (1.f / 2048.f);
    }
    __syncthreads();
    // bias prologue: thread == stacked row m (0..127 = Wn, 128..255 = D)
    float s0 = 0.f, s1 = 0.f, s2 = 0.f;
#pragma unroll 16
    for (int c = 0; c < 128; ++c) {
      float x = Wt[c * 256 + tid];
      s0 = fmaf(x, spool[c * 3 + 0], s0);
      s1 = fmaf(x, spool[c * 3 + 1], s1);
      s2 = fmaf(x, spool[c * 3 + 2], s2);
    }
    sb[tid * 3 + 0] = s0;
    sb[tid * 3 + 1] = s1;
    sb[tid * 3 + 2] = s2;
    __syncthreads();
  }

#pragma unroll
  for (int t = 0; t < 2; ++t) {
    float res[3][4];
#pragma unroll
    for (int r = 0; r < 4; ++r) {
      int o = 32 * w + 16 * t + 4 * q + r;
      float pv[3], dvv[3];
#pragma unroll
      for (int v = 0; v < 3; ++v) {
        pv[v] = acc[t][0][v][r] + (HASPOOL ? sb[o * 3 + v] : 0.f);
        dvv[v] = acc[t][1][v][r] + (HASPOOL ? sb[(128 + o) * 3 + v] : 0.f);
      }
      float dot = fmaf(pv[0], dvv[0], fmaf(pv[1], dvv[1], pv[2] * dvv[2]));
      float dns = fmaf(dvv[0], dvv[0], fmaf(dvv[1], dvv[1], dvv[2] * dvv[2]));
      float f = (dot < 0.f) ? dot / (dns + 1e-6f) : 0.f;
#pragma unroll
      for (int v = 0; v < 3; ++v) res[v][r] = pv[v] - f * dvv[v];
    }
    int o0 = 32 * w + 16 * t + 4 * q;
#pragma unroll
    for (int v = 0; v < 3; ++v) {
      f32x4 rv = {res[v][0], res[v][1], res[v][2], res[v][3]};
      *(f32x4*)(ot + (v * 16 + cl) * LDO + o0) = rv;
    }
  }
  __syncthreads();

  int shadow = (nt & 7) * 3072;
  for (int s = tid; s < 384; s += 256) {
    int o = s / 3, v = s % 3;
    float a2 = 0.f;
#pragma unroll
    for (int c = 0; c < 16; ++c) a2 += ot[(v * 16 + c) * LDO + o];
    if (LAST) atomicAdd(outs + shadow + b * 384 + s, a2);
    else      atomicAdd(pool + shadow + b * 384 + s, a2);
  }

  // drain this block's atomics (all waves), then ARRIVE before repacking —
  // peers' waits clear while we still have local work to do.
  __syncthreads();
  if (arrive_cnt != nullptr && tid == 0) {
    __hip_atomic_fetch_add(arrive_cnt, 1u, __ATOMIC_RELAXED,
                           __HIP_MEMORY_SCOPE_AGENT);
  }

  if constexpr (!LAST) {
    // ot reads all completed at the arrive-sync; in-place repack is safe.
    for (int s = tid; s < 1536; s += 256) {
      int pix = s >> 5, c4 = s & 31;
      float4 sv = *(float4*)(ot + pix * LDO + c4 * 4);
      uint4 vv;
      vv.x = packhl(sv.x);
      vv.y = packhl(sv.y);
      vv.z = packhl(sv.z);
      vv.w = packhl(sv.w);
      // same 16 bytes we just read: LDO*4 == 264*2 == 528-byte rows
      *(uint4*)(xt + pix * 264 + c4 * 8) = vv;
    }
  }
}

// ---------------------------------------------------------------------------
// FUSED kernel: layer1 -> (arrive) -> layer2 [K-loop, then per-batch wait]
// -> (arrive) -> layer3 -> last-block merge.  Activation tile never leaves
// LDS; barrier waits hidden behind the MFMA K-loops.  Plain launch.
// Co-residency by construction: VGPR<=128, LDS 30208 B -> 4 blocks/CU x 256.
// ---------------------------------------------------------------------------
__global__ __launch_bounds__(256, 4) void vnt_stack_kernel(
    float* __restrict__ ws, float* __restrict__ out) {
  __shared__ __align__(16) char smem[48 * 132 * 4];  // 25344 B, dual-purpose
  __shared__ float sb[768];
  __shared__ float spool[384];
  __shared__ unsigned int last_flag;
  int tid = threadIdx.x;
  int bid = blockIdx.x;
  int b = bid >> 7;
  int nt = bid & 127;
  int p0 = nt * 48;
  unsigned short* xt = (unsigned short*)smem;
  unsigned int* bar = (unsigned int*)(ws + OBAR);
  unsigned int* cnt1 = bar + b * 32;         // per-batch, 128-B spaced
  unsigned int* cnt2 = bar + 256 + b * 32;   // per-batch, 128-B spaced
  unsigned int* cntm = bar + 512;            // global merge counter

  // layer1: K2=128, stage from global Xp0; arrive on cnt1; repack into LDS
  vnt_layer_body<128, false, false, true>(
      xt, sb, spool,
      (const unsigned short*)(ws + OXP0), (const unsigned short*)(ws + OWB1),
      nullptr, nullptr, ws + OPS1, nullptr,
      nullptr, cnt1, b, nt, p0, tid);

  // layer2: K2=256, tile in LDS; K-loop first, then wait cnt1; arrive cnt2
  vnt_layer_body<256, true, false, false>(
      xt, sb, spool,
      nullptr, (const unsigned short*)(ws + OWB2),
      ws + OPS1, ws + OWT2, ws + OPS2, nullptr,
      cnt1, cnt2, b, nt, p0, tid);

  // layer3: K2=256; K-loop first, then wait cnt2; outs shadows
  vnt_layer_body<256, true, true, false>(
      xt, sb, spool,
      nullptr, (const unsigned short*)(ws + OWB3),
      ws + OPS2, ws + OWT3, nullptr, ws + OOUTS,
      cnt2, nullptr, b, nt, p0, tid);

  // last-arriving block performs the merge; everyone else just exits.
  // (body already drained outs atomics at its final __syncthreads)
  if (tid == 0) {
    unsigned old = __hip_atomic_fetch_add(cntm, 1u, __ATOMIC_RELAXED,
                                          __HIP_MEMORY_SCOPE_AGENT);
    last_flag = (old == (unsigned)GRID_VNT - 1) ? 1u : 0u;
  }
  __syncthreads();
  if (last_flag) {
    const float* outs = ws + OOUTS;
    for (int idx = tid; idx < B * 384; idx += 256) {
      float s = 0.f;
#pragma unroll
      for (int k = 0; k < 8; ++k) s += cohload(&outs[k * 3072 + idx]);
      out[idx] = s * (1.f / 2048.f);
    }
  }
}

// ---------------------------------------------------------------------------
// launch
// ---------------------------------------------------------------------------
extern "C" void kernel_launch(void* const* d_in, const int* in_sizes, int n_in,
                              void* d_out, int out_size, void* d_ws, size_t ws_size,
                              hipStream_t stream) {
  (void)in_sizes; (void)n_in; (void)out_size; (void)ws_size;
  const float* pc   = (const float*)d_in[0];
  const float* Wpos = (const float*)d_in[1];
  const float* Dpos = (const float*)d_in[2];
  const float* W1   = (const float*)d_in[3];
  const float* D1   = (const float*)d_in[4];
  const float* W2   = (const float*)d_in[5];
  const float* D2   = (const float*)d_in[6];
  const float* W3   = (const float*)d_in[7];
  const float* D3   = (const float*)d_in[8];
  float* out = (float*)d_out;
  float* ws  = (float*)d_ws;

  // fused prep + KNN + edge + pos layer -> Xp0 (+ packed weights, zeroed
  // shadows AND barrier counters)
  knn_edge_kernel<<<dim3(N / QPW, B), 512, 0, stream>>>(
      pc, Wpos, Dpos, W1, D1, W2, D2, W3, D3, ws);

  // fused 3-layer VNT stack + last-block merge (plain launch; per-batch
  // arrive/wait counters hidden behind the MFMA K-loops)
  vnt_stack_kernel<<<GRID_VNT, 256, 0, stream>>>(ws, out);
}

// Round 5
// 172.403 us; speedup vs baseline: 3.9863x; 1.0850x over previous
//
#include <hip/hip_runtime.h>
#include <hip/hip_bf16.h>
#include <math.h>

// ---------------------------------------------------------------------------
// Problem constants
// ---------------------------------------------------------------------------
constexpr int B = 8;
constexpr int N = 2048;
constexpr int KNN = 20;
constexpr int H = 128;
constexpr int P = 3 * N;  // 6144 pixels per batch
constexpr int QPW = 8;    // queries (waves) per knn_edge block

// ws layout (float offsets)
constexpr int OWT2   = 8448;      // W2/D2 second-half TRANSPOSED [c<128][m<256] (32768)
constexpr int OWT3   = 41216;     // W3/D3 second-half transposed (32768)
constexpr int OPS1   = 73984;     // poolsum1 shadows [8][B][128][3] = 24576
constexpr int OPS2   = 98560;     // poolsum2 shadows = 24576
constexpr int OOUTS  = 123136;    // out shadows [8][B][384] = 24576
constexpr int OBAR   = 147712;    // barrier counters: [2][8] per-batch (32-f spaced) + merge (1024 f reserved)
constexpr int OWB1   = 160000;    // Wbig1 bf16 hi/lo, FRAGMENT-MAJOR [ks][256][32h] (16384 f)
constexpr int OWB2   = 176384;    // Wbig2 fragment-major (32768 f)
constexpr int OWB3   = 209152;    // Wbig3 fragment-major (32768 f)
constexpr int OXP0   = 569600;    // Xp0 bf16 [b][P][128] (3145728 f-equiv)

constexpr int ZERO_BASE = OPS1;   // zeroed region = ps1+ps2+outs+barriers
constexpr int ZERO_CNT  = 74752;  // 73728 shadows + 1024 barrier words

constexpr int GRID_VNT  = 1024;   // 4 blocks/CU x 256 CU, exactly co-resident
constexpr int BLK_PER_B = 128;    // blocks per batch (per-batch barrier target)

typedef __attribute__((ext_vector_type(8))) short bf16x8;
typedef __attribute__((ext_vector_type(4))) float f32x4;

__device__ __forceinline__ unsigned short f2bf(float x) {
  __hip_bfloat16 h = __float2bfloat16(x);
  return *(unsigned short*)&h;
}
__device__ __forceinline__ float bf2f(unsigned short u) {
  __hip_bfloat16 h;
  *(unsigned short*)&h = u;
  return __bfloat162float(h);
}
// pack x as (hi, lo) bf16 pair in one uint (hi at lower address)
__device__ __forceinline__ unsigned int packhl(float x) {
  unsigned short hi = f2bf(x);
  float lo = x - bf2f(hi);
  unsigned short ls = f2bf(lo);
  return (unsigned)hi | ((unsigned)ls << 16);
}

// coherent-point read (no cache-maintenance instructions)
__device__ __forceinline__ float cohload(const float* p) {
  return __hip_atomic_load(p, __ATOMIC_RELAXED, __HIP_MEMORY_SCOPE_AGENT);
}

// ---------------------------------------------------------------------------
// Wave-wide bitonic sort of 64 u64 keys, descending (larger key = better).
// Key = ord(value)<<32 | ~index  ==>  value desc, ties -> smaller index.
// ---------------------------------------------------------------------------
__device__ __forceinline__ void wave_sort_key(unsigned long long& k, int lane) {
#pragma unroll
  for (int kk = 2; kk <= 64; kk <<= 1) {
#pragma unroll
    for (int j = kk >> 1; j > 0; j >>= 1) {
      unsigned long long pk =
          (unsigned long long)__shfl_xor((long long)k, j);
      bool iam_lower   = (lane & j) == 0;
      bool dir_desc    = (lane & kk) == 0;
      bool p_better    = pk > k;
      bool want_better = (dir_desc == iam_lower);
      k = (p_better == want_better) ? pk : k;
    }
  }
}

// ---------------------------------------------------------------------------
// K2 (FUSED): prep + exact top-20 KNN + edge + pos layer + mean-k -> Xp0.
// (unchanged from the verified version)
// ---------------------------------------------------------------------------
__global__ __launch_bounds__(512, 8) void knn_edge_kernel(
    const float* __restrict__ pc, const float* __restrict__ Wpos,
    const float* __restrict__ Dp,
    const float* __restrict__ W1, const float* __restrict__ D1,
    const float* __restrict__ W2, const float* __restrict__ D2,
    const float* __restrict__ W3, const float* __restrict__ D3,
    float* __restrict__ ws) {
  __shared__ float4 spt[N];                       // 32 KB (2x,2y,2z,xx)
  __shared__ __align__(16) unsigned char sphase[QPW][640];   // 5 KB
  int tid = threadIdx.x;
  int b = blockIdx.y;
  int bid = blockIdx.y * gridDim.x + blockIdx.x;  // 0..2047
  int wv = tid >> 6, lane = tid & 63;
  unsigned short* Xp0 = (unsigned short*)(ws + OXP0);
  unsigned short* sbufw = (unsigned short*)sphase[wv];
  float4* erw = (float4*)sphase[wv];

  // hoisted edge-phase weight loads (latency hidden under distance pass)
  int o = lane;
  float w0 = Wpos[o * 3 + 0], w1 = Wpos[o * 3 + 1], w2 = Wpos[o * 3 + 2];
  float e0 = Dp[o * 3 + 0], e1 = Dp[o * 3 + 1], e2 = Dp[o * 3 + 2];

  // ---- folded prep: distributed shadow+barrier zeroing (1 store/thread) ---
  {
    int zi = bid * 512 + tid;
    if (zi < ZERO_CNT) ws[ZERO_BASE + zi] = 0.f;
  }
  // ---- folded prep: 768 weight rows over blocks 0..95 (one wave/row) -----
  if (bid < 96) {
    int rr = bid * 8 + wv;  // 0..767
    const float* src;
    float* tdst = nullptr;
    unsigned int* pdst;   // base of fragment-major region + m*16
    int C, Cpack;
    bool norm;
    if (rr < 128)      { src = W1 + rr * 64;            C = 64;  Cpack = 64;  norm = true;
                         pdst = (unsigned int*)(ws + OWB1) + rr * 16; }
    else if (rr < 256) { int m = rr - 128; src = D1 + m * 64;  C = 64;  Cpack = 64;  norm = false;
                         pdst = (unsigned int*)(ws + OWB1) + (m + 128) * 16; }
    else if (rr < 384) { int m = rr - 256; src = W2 + m * 256; C = 256; Cpack = 128; norm = true;
                         pdst = (unsigned int*)(ws + OWB2) + m * 16; tdst = ws + OWT2 + m; }
    else if (rr < 512) { int m = rr - 384; src = D2 + m * 256; C = 256; Cpack = 128; norm = false;
                         pdst = (unsigned int*)(ws + OWB2) + (m + 128) * 16; tdst = ws + OWT2 + 128 + m; }
    else if (rr < 640) { int m = rr - 512; src = W3 + m * 256; C = 256; Cpack = 128; norm = true;
                         pdst = (unsigned int*)(ws + OWB3) + m * 16; tdst = ws + OWT3 + m; }
    else               { int m = rr - 640; src = D3 + m * 256; C = 256; Cpack = 128; norm = false;
                         pdst = (unsigned int*)(ws + OWB3) + (m + 128) * 16; tdst = ws + OWT3 + 128 + m; }
    float s = 1.f;
    if (norm) {
      float a = 0.f;
      for (int i = lane; i < C; i += 64) a += src[i];
#pragma unroll
      for (int off = 32; off > 0; off >>= 1) a += __shfl_xor(a, off);
      s = a;
    }
    for (int i = lane; i < C; i += 64) {
      float val = src[i] / s;  // exact when s==1
      if (i < Cpack) pdst[(i >> 4) * 4096 + (i & 15)] = packhl(val);
      if (tdst && i >= 128) tdst[(i - 128) * 256] = val;
    }
  }

  // ---- stage point cloud ---------------------------------------------------
  const float* pcb = pc + (size_t)b * N * 3;
  for (int i = tid; i < N; i += 512) {
    float x = pcb[i * 3 + 0], y = pcb[i * 3 + 1], z = pcb[i * 3 + 2];
    float xx = __fadd_rn(__fadd_rn(__fmul_rn(x, x), __fmul_rn(y, y)), __fmul_rn(z, z));
    spt[i] = make_float4(2.f * x, 2.f * y, 2.f * z, xx);
  }
  __syncthreads();
  int q = blockIdx.x * QPW + wv;
  float4 qp = spt[q];
  float qx = 0.5f * qp.x, qy = 0.5f * qp.y, qz = 0.5f * qp.z, qxx = qp.w;

  float dv[32];
  float lmax = -INFINITY;
#pragma unroll
  for (int i = 0; i < 32; ++i) {
    float4 m = spt[i * 64 + lane];
    float A = __fadd_rn(__fadd_rn(__fmul_rn(m.x, qx), __fmul_rn(m.y, qy)),
                        __fmul_rn(m.z, qz));
    float d = __fsub_rn(__fsub_rn(A, qxx), m.w);
    dv[i] = d;
    lmax = fmaxf(lmax, d);
  }

  // value-only bitonic sort (descending) of the 64 lane-maxes; take #19
  float sv = lmax;
#pragma unroll
  for (int k = 2; k <= 64; k <<= 1) {
#pragma unroll
    for (int j = k >> 1; j > 0; j >>= 1) {
      float pv = __shfl_xor(sv, j);
      bool keep_max = ((lane & k) == 0) == ((lane & j) == 0);
      sv = keep_max ? fmaxf(sv, pv) : fminf(sv, pv);
    }
  }
  float tval = __shfl(sv, 19);  // 20th-largest lane-max <= V20 (provable)

  // registerized compact: per-lane survivor mask + shfl prefix scan
  unsigned msk = 0u;
#pragma unroll
  for (int i = 0; i < 32; ++i) msk |= (dv[i] >= tval) ? (1u << i) : 0u;
  int cnt = __popc(msk);
  int scan = cnt;
#pragma unroll
  for (int off = 1; off < 64; off <<= 1) {
    int t = __shfl_up(scan, off);
    scan += (lane >= off) ? t : 0;
  }
  int S = __shfl(scan, 63);
  int pos = scan - cnt;  // exclusive prefix
  unsigned mm = msk;
  while (mm) {
    int i = __ffs(mm) - 1;
    mm &= mm - 1;
    if (pos < 192) sbufw[pos] = (unsigned short)(i * 64 + lane);
    ++pos;
  }

  auto distOf = [&](int m) -> float {
    float4 mp = spt[m];
    float A = __fadd_rn(__fadd_rn(__fmul_rn(mp.x, qx), __fmul_rn(mp.y, qy)),
                        __fmul_rn(mp.z, qz));
    return __fsub_rn(__fsub_rn(A, qxx), mp.w);
  };
  auto mkkey = [&](int m) -> unsigned long long {
    float d = distOf(m);
    unsigned u = __float_as_uint(d);
    u ^= (u >> 31) ? 0xFFFFFFFFu : 0x80000000u;
    return ((unsigned long long)u << 32) | (unsigned)(~m);
  };

  unsigned long long key = 0ULL;  // padding key: below every real key
  if (S <= 64) {
    if (lane < S) key = mkkey(sbufw[lane]);
    wave_sort_key(key, lane);
  } else if (S <= 192) {
    int p2 = 0;
    while (p2 < S) {
      if (lane >= KNN) {
        int t = p2 + lane - KNN;
        key = (t < S) ? mkkey(sbufw[t]) : 0ULL;
      }
      wave_sort_key(key, lane);
      p2 += 64 - KNN;
    }
  } else {
    int p2 = 0;
    while (p2 < N) {
      if (lane >= KNN) {
        int t = p2 + lane - KNN;
        key = (t < N) ? mkkey(t) : 0ULL;
      }
      wave_sort_key(key, lane);
      p2 += 64 - KNN;
    }
  }
  int cm = ~((unsigned)key);  // valid in lanes 0..19

  // ---- edge geometry precompute: lane k<20 computes e/r once --------------
  if (lane < KNN) {
    float4 t = spt[cm];
    float nx = 0.5f * t.x, ny = 0.5f * t.y, nz = 0.5f * t.z;
    float ex = nx - qx, ey = ny - qy, ez = nz - qz;
    float rx = ny * qz - nz * qy;
    float ry = nz * qx - nx * qz;
    float rz = nx * qy - ny * qx;
    erw[2 * lane + 0] = make_float4(ex, ey, ez, 0.f);
    erw[2 * lane + 1] = make_float4(rx, ry, rz, 0.f);
  }

  // ---- edge + pos layer (lane o = channel o) -------------------------------
  {
    float s = (w0 + w2) + w1;
    w0 = w0 / s; w1 = w1 / s; w2 = w2 / s;
  }
  float cx = qx, cy = qy, cz = qz;  // exact raw coords (0.5 * 2x)
  float pcx = w1 * cx, pcy = w1 * cy, pcz = w1 * cz;
  float dcx = e1 * cx, dcy = e1 * cy, dcz = e1 * cz;
  float ax = 0.f, ay = 0.f, az = 0.f;
#pragma unroll 4
  for (int k = 0; k < KNN; ++k) {
    float4 e4 = erw[2 * k + 0];   // broadcast LDS reads
    float4 r4 = erw[2 * k + 1];
    float ex = e4.x, ey = e4.y, ez = e4.z;
    float rx = r4.x, ry = r4.y, rz = r4.z;
    float px = fmaf(w0, ex, fmaf(w2, rx, pcx));
    float py = fmaf(w0, ey, fmaf(w2, ry, pcy));
    float pz = fmaf(w0, ez, fmaf(w2, rz, pcz));
    float dx = fmaf(e0, ex, fmaf(e2, rx, dcx));
    float dy = fmaf(e0, ey, fmaf(e2, ry, dcy));
    float dz = fmaf(e0, ez, fmaf(e2, rz, dcz));
    float dot = fmaf(px, dx, fmaf(py, dy, pz * dz));
    float dns = fmaf(dx, dx, fmaf(dy, dy, dz * dz)) + 1e-6f;
    float r0 = __builtin_amdgcn_rcpf(dns);
    r0 = r0 * fmaf(-dns, r0, 2.0f);          // 1 Newton step
    float f = (dot < 0.f) ? dot * r0 : 0.f;
    ax = fmaf(-f, dx, px) + ax;
    ay = fmaf(-f, dy, py) + ay;
    az = fmaf(-f, dz, pz) + az;
  }
  int pbase = ((q >> 4) * 48) + (q & 15);
  unsigned short* dst = Xp0 + ((size_t)b * P + pbase) * 128 + 2 * o;
  *(unsigned int*)(dst)              = packhl(ax * (1.f / 20.f));
  *(unsigned int*)(dst + 16 * 128)   = packhl(ay * (1.f / 20.f));
  *(unsigned int*)(dst + 32 * 128)   = packhl(az * (1.f / 20.f));
}

// ---------------------------------------------------------------------------
// Shared VNT layer body — per-batch early-arrive, wait at layer ENTRY.
//
// Intra-layer order matches the verified non-fused kernel (bias BEFORE the
// K-loop) so the 48-reg accumulator is live only K-loop -> epilogue: no
// scratch spills (round-4 lesson: acc live across the bias loop spilled
// ~34 MB of scratch traffic per launch).
//
// Arrive protocol: each block signals its per-batch counter right after its
// pool atomicAdds (before the LDS repack), so by the time peers finish their
// repack + A-prefetch and hit the next layer's wait, the counter is already
// at target -> near-zero spin, few polls.
//
// GSRC=true : stage the X tile [48][K2] from global Xp into LDS.
// GSRC=false: tile already in LDS (repacked in place by the previous layer).
// In-place repack valid because LDO*4 bytes == (256+8)*2 bytes == 528.
// All cross-block data is written by device-scope atomicAdd (coherent point)
// and read with relaxed agent-scope loads; __syncthreads drains vmcnt before
// tid0 signals.  No cache-maintenance instructions anywhere.
// ---------------------------------------------------------------------------
template <int K2, bool HASPOOL, bool LAST, bool GSRC>
__device__ __forceinline__ void vnt_layer_body(
    unsigned short* xt, float* sb, float* spool,
    const unsigned short* __restrict__ Xp, const unsigned short* __restrict__ Wb,
    const float* __restrict__ ps, const float* __restrict__ Wt,
    float* __restrict__ pool, float* __restrict__ outs,
    unsigned int* wait_cnt, unsigned int* arrive_cnt,
    int b, int nt, int p0, int tid) {
  constexpr int KS = K2 / 32;
  constexpr int LDR = K2 + 8;   // halves; X-tile row stride
  constexpr int LDO = 132;      // floats; out-tile row stride
  float* ot = (float*)xt;
  int w = tid >> 6, lane = tid & 63;
  int q = lane >> 4, cl = lane & 15;

  if constexpr (GSRC) {
    // stage X tile [48][K2] -> LDS
    for (int ch = tid; ch < 48 * (K2 / 8); ch += 256) {
      int rp = ch / (K2 / 8), cc = ch % (K2 / 8);
      *(uint4*)(xt + rp * LDR + cc * 8) =
          *(const uint4*)(Xp + ((size_t)b * P + p0 + rp) * K2 + cc * 8);
    }
  }

  // first A-fragments: global, LDS-independent -> issue before wait/barrier
  bf16x8 acur[2][2], anxt[2][2];
#pragma unroll
  for (int t = 0; t < 2; ++t)
#pragma unroll
    for (int pd = 0; pd < 2; ++pd)
      acur[t][pd] = *(const bf16x8*)(Wb +
          (size_t)(32 * w + 16 * t + 128 * pd + cl) * 32 + q * 8);

  // per-batch wait at layer entry: peers arrived before their repack, so
  // expected spin ~ 0.  tid0 polls; other threads park at the barrier.
  if constexpr (HASPOOL) {
    if (tid == 0) {
      while (__hip_atomic_load(wait_cnt, __ATOMIC_RELAXED,
                               __HIP_MEMORY_SCOPE_AGENT) < (unsigned)BLK_PER_B) {
        __builtin_amdgcn_s_sleep(2);
      }
    }
  }
  __syncthreads();  // staging/repack visible + wait satisfied

  if constexpr (HASPOOL) {
    // pooled mean (sum of 8 shadow copies, coherent-point reads) -> LDS
    for (int i = tid; i < 384; i += 256) {
      float x = 0.f;
#pragma unroll
      for (int k = 0; k < 8; ++k)
        x += cohload(&ps[k * 3072 + b * 384 + i]);
      spool[i] = x * (1.f / 2048.f);
    }
    __syncthreads();
    // bias prologue: thread == stacked row m (0..127 = Wn, 128..255 = D)
    float s0 = 0.f, s1 = 0.f, s2 = 0.f;
#pragma unroll 16
    for (int c = 0; c < 128; ++c) {
      float x = Wt[c * 256 + tid];
      s0 = fmaf(x, spool[c * 3 + 0], s0);
      s1 = fmaf(x, spool[c * 3 + 1], s1);
      s2 = fmaf(x, spool[c * 3 + 2], s2);
    }
    sb[tid * 3 + 0] = s0;
    sb[tid * 3 + 1] = s1;
    sb[tid * 3 + 2] = s2;
    __syncthreads();
  }

  f32x4 acc[2][2][3] = {};  // [t][pd][v]

#pragma unroll
  for (int ks = 0; ks < KS; ++ks) {
    if (ks + 1 < KS) {
#pragma unroll
      for (int t = 0; t < 2; ++t)
#pragma unroll
        for (int pd = 0; pd < 2; ++pd)
          anxt[t][pd] = *(const bf16x8*)(Wb +
              (size_t)(32 * w + 16 * t + 128 * pd + cl) * 32 + q * 8 +
              (ks + 1) * 8192);
    }
    bf16x8 bb[3];
#pragma unroll
    for (int v = 0; v < 3; ++v)
      bb[v] = *(const bf16x8*)(xt + (v * 16 + cl) * LDR + ks * 32 + q * 8);
#pragma unroll
    for (int t = 0; t < 2; ++t)
#pragma unroll
      for (int pd = 0; pd < 2; ++pd)
#pragma unroll
        for (int v = 0; v < 3; ++v)
          acc[t][pd][v] = __builtin_amdgcn_mfma_f32_16x16x32_bf16(
              acur[t][pd], bb[v], acc[t][pd][v], 0, 0, 0);
#pragma unroll
    for (int t = 0; t < 2; ++t)
#pragma unroll
      for (int pd = 0; pd < 2; ++pd)
        acur[t][pd] = anxt[t][pd];
  }
  __syncthreads();  // X-tile dead; buffer becomes the fp32 out-tile

#pragma unroll
  for (int t = 0; t < 2; ++t) {
    float res[3][4];
#pragma unroll
    for (int r = 0; r < 4; ++r) {
      int o = 32 * w + 16 * t + 4 * q + r;
      float pv[3], dvv[3];
#pragma unroll
      for (int v = 0; v < 3; ++v) {
        pv[v] = acc[t][0][v][r] + (HASPOOL ? sb[o * 3 + v] : 0.f);
        dvv[v] = acc[t][1][v][r] + (HASPOOL ? sb[(128 + o) * 3 + v] : 0.f);
      }
      float dot = fmaf(pv[0], dvv[0], fmaf(pv[1], dvv[1], pv[2] * dvv[2]));
      float dns = fmaf(dvv[0], dvv[0], fmaf(dvv[1], dvv[1], dvv[2] * dvv[2]));
      float f = (dot < 0.f) ? dot / (dns + 1e-6f) : 0.f;
#pragma unroll
      for (int v = 0; v < 3; ++v) res[v][r] = pv[v] - f * dvv[v];
    }
    int o0 = 32 * w + 16 * t + 4 * q;
#pragma unroll
    for (int v = 0; v < 3; ++v) {
      f32x4 rv = {res[v][0], res[v][1], res[v][2], res[v][3]};
      *(f32x4*)(ot + (v * 16 + cl) * LDO + o0) = rv;
    }
  }
  __syncthreads();

  int shadow = (nt & 7) * 3072;
  for (int s = tid; s < 384; s += 256) {
    int o = s / 3, v = s % 3;
    float a2 = 0.f;
#pragma unroll
    for (int c = 0; c < 16; ++c) a2 += ot[(v * 16 + c) * LDO + o];
    if (LAST) atomicAdd(outs + shadow + b * 384 + s, a2);
    else      atomicAdd(pool + shadow + b * 384 + s, a2);
  }

  // drain this block's atomics (all waves), then ARRIVE before repacking —
  // peers' waits clear while we still have local work (repack) to do.
  __syncthreads();
  if (arrive_cnt != nullptr && tid == 0) {
    __hip_atomic_fetch_add(arrive_cnt, 1u, __ATOMIC_RELAXED,
                           __HIP_MEMORY_SCOPE_AGENT);
  }

  if constexpr (!LAST) {
    // ot reads all completed at the arrive-sync; in-place repack is safe.
    for (int s = tid; s < 1536; s += 256) {
      int pix = s >> 5, c4 = s & 31;
      float4 sv = *(float4*)(ot + pix * LDO + c4 * 4);
      uint4 vv;
      vv.x = packhl(sv.x);
      vv.y = packhl(sv.y);
      vv.z = packhl(sv.z);
      vv.w = packhl(sv.w);
      // same 16 bytes we just read: LDO*4 == 264*2 == 528-byte rows
      *(uint4*)(xt + pix * 264 + c4 * 8) = vv;
    }
  }
}

// ---------------------------------------------------------------------------
// FUSED kernel: layer1 -> (arrive) -> layer2 [wait@entry, bias, K-loop] ->
// (arrive) -> layer3 -> last-block merge.  Activation tile never leaves LDS.
// Co-residency by construction: VGPR<=128, LDS 30208 B -> 4 blocks/CU x 256.
// ---------------------------------------------------------------------------
__global__ __launch_bounds__(256, 4) void vnt_stack_kernel(
    float* __restrict__ ws, float* __restrict__ out) {
  __shared__ __align__(16) char smem[48 * 132 * 4];  // 25344 B, dual-purpose
  __shared__ float sb[768];
  __shared__ float spool[384];
  __shared__ unsigned int last_flag;
  int tid = threadIdx.x;
  int bid = blockIdx.x;
  int b = bid >> 7;
  int nt = bid & 127;
  int p0 = nt * 48;
  unsigned short* xt = (unsigned short*)smem;
  unsigned int* bar = (unsigned int*)(ws + OBAR);
  unsigned int* cnt1 = bar + b * 32;         // per-batch, 128-B spaced
  unsigned int* cnt2 = bar + 256 + b * 32;   // per-batch, 128-B spaced
  unsigned int* cntm = bar + 512;            // global merge counter

  // layer1: K2=128, stage from global Xp0; arrive on cnt1; repack into LDS
  vnt_layer_body<128, false, false, true>(
      xt, sb, spool,
      (const unsigned short*)(ws + OXP0), (const unsigned short*)(ws + OWB1),
      nullptr, nullptr, ws + OPS1, nullptr,
      nullptr, cnt1, b, nt, p0, tid);

  // layer2: K2=256, tile in LDS; wait cnt1 at entry; arrive cnt2
  vnt_layer_body<256, true, false, false>(
      xt, sb, spool,
      nullptr, (const unsigned short*)(ws + OWB2),
      ws + OPS1, ws + OWT2, ws + OPS2, nullptr,
      cnt1, cnt2, b, nt, p0, tid);

  // layer3: K2=256; wait cnt2 at entry; outs shadows
  vnt_layer_body<256, true, true, false>(
      xt, sb, spool,
      nullptr, (const unsigned short*)(ws + OWB3),
      ws + OPS2, ws + OWT3, nullptr, ws + OOUTS,
      cnt2, nullptr, b, nt, p0, tid);

  // last-arriving block performs the merge; everyone else just exits.
  // (body already drained outs atomics at its final __syncthreads)
  if (tid == 0) {
    unsigned old = __hip_atomic_fetch_add(cntm, 1u, __ATOMIC_RELAXED,
                                          __HIP_MEMORY_SCOPE_AGENT);
    last_flag = (old == (unsigned)GRID_VNT - 1) ? 1u : 0u;
  }
  __syncthreads();
  if (last_flag) {
    const float* outs = ws + OOUTS;
    for (int idx = tid; idx < B * 384; idx += 256) {
      float s = 0.f;
#pragma unroll
      for (int k = 0; k < 8; ++k) s += cohload(&outs[k * 3072 + idx]);
      out[idx] = s * (1.f / 2048.f);
    }
  }
}

// ---------------------------------------------------------------------------
// launch
// ---------------------------------------------------------------------------
extern "C" void kernel_launch(void* const* d_in, const int* in_sizes, int n_in,
                              void* d_out, int out_size, void* d_ws, size_t ws_size,
                              hipStream_t stream) {
  (void)in_sizes; (void)n_in; (void)out_size; (void)ws_size;
  const float* pc   = (const float*)d_in[0];
  const float* Wpos = (const float*)d_in[1];
  const float* Dpos = (const float*)d_in[2];
  const float* W1   = (const float*)d_in[3];
  const float* D1   = (const float*)d_in[4];
  const float* W2   = (const float*)d_in[5];
  const float* D2   = (const float*)d_in[6];
  const float* W3   = (const float*)d_in[7];
  const float* D3   = (const float*)d_in[8];
  float* out = (float*)d_out;
  float* ws  = (float*)d_ws;

  // fused prep + KNN + edge + pos layer -> Xp0 (+ packed weights, zeroed
  // shadows AND barrier counters)
  knn_edge_kernel<<<dim3(N / QPW, B), 512, 0, stream>>>(
      pc, Wpos, Dpos, W1, D1, W2, D2, W3, D3, ws);

  // fused 3-layer VNT stack + last-block merge (plain launch; per-batch
  // early-arrive / entry-wait counters)
  vnt_stack_kernel<<<GRID_VNT, 256, 0, stream>>>(ws, out);
}

// Round 6
// 164.220 us; speedup vs baseline: 4.1850x; 1.0498x over previous
//
#include <hip/hip_runtime.h>
#include <hip/hip_bf16.h>
#include <math.h>

// ---------------------------------------------------------------------------
// Problem constants
// ---------------------------------------------------------------------------
constexpr int B = 8;
constexpr int N = 2048;
constexpr int KNN = 20;
constexpr int H = 128;
constexpr int P = 3 * N;  // 6144 pixels per batch
constexpr int QPW = 8;    // queries (waves) per knn_edge block

// ws layout (float offsets)
constexpr int OSB2   = 0;         // published sb for layer2 [B][768] (6144 f; region [0,8448) was free)
constexpr int OWT2   = 8448;      // W2/D2 second-half TRANSPOSED [c<128][m<256] (32768)
constexpr int OWT3   = 41216;     // W3/D3 second-half transposed (32768)
constexpr int OPS1   = 73984;     // poolsum1 shadows [8][B][128][3] = 24576
constexpr int OPS2   = 98560;     // poolsum2 shadows = 24576
constexpr int OOUTS  = 123136;    // out shadows [8][B][384] = 24576
constexpr int OBAR   = 147712;    // barrier counters/flags (1024 f reserved)
constexpr int OSB3   = 148736;    // published sb for layer3 [B][768] (6144 f; fits before OWB1)
constexpr int OWB1   = 160000;    // Wbig1 bf16 hi/lo, FRAGMENT-MAJOR [ks][256][32h] (16384 f)
constexpr int OWB2   = 176384;    // Wbig2 fragment-major (32768 f)
constexpr int OWB3   = 209152;    // Wbig3 fragment-major (32768 f)
constexpr int OXP0   = 569600;    // Xp0 bf16 [b][P][128] (3145728 f-equiv)

constexpr int ZERO_BASE = OPS1;   // zeroed region = ps1+ps2+outs+barriers
constexpr int ZERO_CNT  = 74752;  // 73728 shadows + 1024 barrier words
// (OSB2/OSB3 need no zeroing: strictly write-before-read each launch)

constexpr int GRID_VNT  = 1024;   // 4 blocks/CU x 256 CU, exactly co-resident
constexpr int BLK_PER_B = 128;    // blocks per batch (per-batch barrier target)

typedef __attribute__((ext_vector_type(8))) short bf16x8;
typedef __attribute__((ext_vector_type(4))) float f32x4;

__device__ __forceinline__ unsigned short f2bf(float x) {
  __hip_bfloat16 h = __float2bfloat16(x);
  return *(unsigned short*)&h;
}
__device__ __forceinline__ float bf2f(unsigned short u) {
  __hip_bfloat16 h;
  *(unsigned short*)&h = u;
  return __bfloat162float(h);
}
// pack x as (hi, lo) bf16 pair in one uint (hi at lower address)
__device__ __forceinline__ unsigned int packhl(float x) {
  unsigned short hi = f2bf(x);
  float lo = x - bf2f(hi);
  unsigned short ls = f2bf(lo);
  return (unsigned)hi | ((unsigned)ls << 16);
}

// coherent-point read/write (no cache-maintenance instructions)
__device__ __forceinline__ float cohload(const float* p) {
  return __hip_atomic_load(p, __ATOMIC_RELAXED, __HIP_MEMORY_SCOPE_AGENT);
}
__device__ __forceinline__ void cohstore(float* p, float v) {
  __hip_atomic_store(p, v, __ATOMIC_RELAXED, __HIP_MEMORY_SCOPE_AGENT);
}

// ---------------------------------------------------------------------------
// Wave-wide bitonic sort of 64 u64 keys, descending (larger key = better).
// Key = ord(value)<<32 | ~index  ==>  value desc, ties -> smaller index.
// ---------------------------------------------------------------------------
__device__ __forceinline__ void wave_sort_key(unsigned long long& k, int lane) {
#pragma unroll
  for (int kk = 2; kk <= 64; kk <<= 1) {
#pragma unroll
    for (int j = kk >> 1; j > 0; j >>= 1) {
      unsigned long long pk =
          (unsigned long long)__shfl_xor((long long)k, j);
      bool iam_lower   = (lane & j) == 0;
      bool dir_desc    = (lane & kk) == 0;
      bool p_better    = pk > k;
      bool want_better = (dir_desc == iam_lower);
      k = (p_better == want_better) ? pk : k;
    }
  }
}

// ---------------------------------------------------------------------------
// K2 (FUSED): prep + exact top-20 KNN + edge + pos layer + mean-k -> Xp0.
// (unchanged from the verified version)
// ---------------------------------------------------------------------------
__global__ __launch_bounds__(512, 8) void knn_edge_kernel(
    const float* __restrict__ pc, const float* __restrict__ Wpos,
    const float* __restrict__ Dp,
    const float* __restrict__ W1, const float* __restrict__ D1,
    const float* __restrict__ W2, const float* __restrict__ D2,
    const float* __restrict__ W3, const float* __restrict__ D3,
    float* __restrict__ ws) {
  __shared__ float4 spt[N];                       // 32 KB (2x,2y,2z,xx)
  __shared__ __align__(16) unsigned char sphase[QPW][640];   // 5 KB
  int tid = threadIdx.x;
  int b = blockIdx.y;
  int bid = blockIdx.y * gridDim.x + blockIdx.x;  // 0..2047
  int wv = tid >> 6, lane = tid & 63;
  unsigned short* Xp0 = (unsigned short*)(ws + OXP0);
  unsigned short* sbufw = (unsigned short*)sphase[wv];
  float4* erw = (float4*)sphase[wv];

  // hoisted edge-phase weight loads (latency hidden under distance pass)
  int o = lane;
  float w0 = Wpos[o * 3 + 0], w1 = Wpos[o * 3 + 1], w2 = Wpos[o * 3 + 2];
  float e0 = Dp[o * 3 + 0], e1 = Dp[o * 3 + 1], e2 = Dp[o * 3 + 2];

  // ---- folded prep: distributed shadow+barrier zeroing (1 store/thread) ---
  {
    int zi = bid * 512 + tid;
    if (zi < ZERO_CNT) ws[ZERO_BASE + zi] = 0.f;
  }
  // ---- folded prep: 768 weight rows over blocks 0..95 (one wave/row) -----
  if (bid < 96) {
    int rr = bid * 8 + wv;  // 0..767
    const float* src;
    float* tdst = nullptr;
    unsigned int* pdst;   // base of fragment-major region + m*16
    int C, Cpack;
    bool norm;
    if (rr < 128)      { src = W1 + rr * 64;            C = 64;  Cpack = 64;  norm = true;
                         pdst = (unsigned int*)(ws + OWB1) + rr * 16; }
    else if (rr < 256) { int m = rr - 128; src = D1 + m * 64;  C = 64;  Cpack = 64;  norm = false;
                         pdst = (unsigned int*)(ws + OWB1) + (m + 128) * 16; }
    else if (rr < 384) { int m = rr - 256; src = W2 + m * 256; C = 256; Cpack = 128; norm = true;
                         pdst = (unsigned int*)(ws + OWB2) + m * 16; tdst = ws + OWT2 + m; }
    else if (rr < 512) { int m = rr - 384; src = D2 + m * 256; C = 256; Cpack = 128; norm = false;
                         pdst = (unsigned int*)(ws + OWB2) + (m + 128) * 16; tdst = ws + OWT2 + 128 + m; }
    else if (rr < 640) { int m = rr - 512; src = W3 + m * 256; C = 256; Cpack = 128; norm = true;
                         pdst = (unsigned int*)(ws + OWB3) + m * 16; tdst = ws + OWT3 + m; }
    else               { int m = rr - 640; src = D3 + m * 256; C = 256; Cpack = 128; norm = false;
                         pdst = (unsigned int*)(ws + OWB3) + (m + 128) * 16; tdst = ws + OWT3 + 128 + m; }
    float s = 1.f;
    if (norm) {
      float a = 0.f;
      for (int i = lane; i < C; i += 64) a += src[i];
#pragma unroll
      for (int off = 32; off > 0; off >>= 1) a += __shfl_xor(a, off);
      s = a;
    }
    for (int i = lane; i < C; i += 64) {
      float val = src[i] / s;  // exact when s==1
      if (i < Cpack) pdst[(i >> 4) * 4096 + (i & 15)] = packhl(val);
      if (tdst && i >= 128) tdst[(i - 128) * 256] = val;
    }
  }

  // ---- stage point cloud ---------------------------------------------------
  const float* pcb = pc + (size_t)b * N * 3;
  for (int i = tid; i < N; i += 512) {
    float x = pcb[i * 3 + 0], y = pcb[i * 3 + 1], z = pcb[i * 3 + 2];
    float xx = __fadd_rn(__fadd_rn(__fmul_rn(x, x), __fmul_rn(y, y)), __fmul_rn(z, z));
    spt[i] = make_float4(2.f * x, 2.f * y, 2.f * z, xx);
  }
  __syncthreads();
  int q = blockIdx.x * QPW + wv;
  float4 qp = spt[q];
  float qx = 0.5f * qp.x, qy = 0.5f * qp.y, qz = 0.5f * qp.z, qxx = qp.w;

  float dv[32];
  float lmax = -INFINITY;
#pragma unroll
  for (int i = 0; i < 32; ++i) {
    float4 m = spt[i * 64 + lane];
    float A = __fadd_rn(__fadd_rn(__fmul_rn(m.x, qx), __fmul_rn(m.y, qy)),
                        __fmul_rn(m.z, qz));
    float d = __fsub_rn(__fsub_rn(A, qxx), m.w);
    dv[i] = d;
    lmax = fmaxf(lmax, d);
  }

  // value-only bitonic sort (descending) of the 64 lane-maxes; take #19
  float sv = lmax;
#pragma unroll
  for (int k = 2; k <= 64; k <<= 1) {
#pragma unroll
    for (int j = k >> 1; j > 0; j >>= 1) {
      float pv = __shfl_xor(sv, j);
      bool keep_max = ((lane & k) == 0) == ((lane & j) == 0);
      sv = keep_max ? fmaxf(sv, pv) : fminf(sv, pv);
    }
  }
  float tval = __shfl(sv, 19);  // 20th-largest lane-max <= V20 (provable)

  // registerized compact: per-lane survivor mask + shfl prefix scan
  unsigned msk = 0u;
#pragma unroll
  for (int i = 0; i < 32; ++i) msk |= (dv[i] >= tval) ? (1u << i) : 0u;
  int cnt = __popc(msk);
  int scan = cnt;
#pragma unroll
  for (int off = 1; off < 64; off <<= 1) {
    int t = __shfl_up(scan, off);
    scan += (lane >= off) ? t : 0;
  }
  int S = __shfl(scan, 63);
  int pos = scan - cnt;  // exclusive prefix
  unsigned mm = msk;
  while (mm) {
    int i = __ffs(mm) - 1;
    mm &= mm - 1;
    if (pos < 192) sbufw[pos] = (unsigned short)(i * 64 + lane);
    ++pos;
  }

  auto distOf = [&](int m) -> float {
    float4 mp = spt[m];
    float A = __fadd_rn(__fadd_rn(__fmul_rn(mp.x, qx), __fmul_rn(mp.y, qy)),
                        __fmul_rn(mp.z, qz));
    return __fsub_rn(__fsub_rn(A, qxx), mp.w);
  };
  auto mkkey = [&](int m) -> unsigned long long {
    float d = distOf(m);
    unsigned u = __float_as_uint(d);
    u ^= (u >> 31) ? 0xFFFFFFFFu : 0x80000000u;
    return ((unsigned long long)u << 32) | (unsigned)(~m);
  };

  unsigned long long key = 0ULL;  // padding key: below every real key
  if (S <= 64) {
    if (lane < S) key = mkkey(sbufw[lane]);
    wave_sort_key(key, lane);
  } else if (S <= 192) {
    int p2 = 0;
    while (p2 < S) {
      if (lane >= KNN) {
        int t = p2 + lane - KNN;
        key = (t < S) ? mkkey(sbufw[t]) : 0ULL;
      }
      wave_sort_key(key, lane);
      p2 += 64 - KNN;
    }
  } else {
    int p2 = 0;
    while (p2 < N) {
      if (lane >= KNN) {
        int t = p2 + lane - KNN;
        key = (t < N) ? mkkey(t) : 0ULL;
      }
      wave_sort_key(key, lane);
      p2 += 64 - KNN;
    }
  }
  int cm = ~((unsigned)key);  // valid in lanes 0..19

  // ---- edge geometry precompute: lane k<20 computes e/r once --------------
  if (lane < KNN) {
    float4 t = spt[cm];
    float nx = 0.5f * t.x, ny = 0.5f * t.y, nz = 0.5f * t.z;
    float ex = nx - qx, ey = ny - qy, ez = nz - qz;
    float rx = ny * qz - nz * qy;
    float ry = nz * qx - nx * qz;
    float rz = nx * qy - ny * qx;
    erw[2 * lane + 0] = make_float4(ex, ey, ez, 0.f);
    erw[2 * lane + 1] = make_float4(rx, ry, rz, 0.f);
  }

  // ---- edge + pos layer (lane o = channel o) -------------------------------
  {
    float s = (w0 + w2) + w1;
    w0 = w0 / s; w1 = w1 / s; w2 = w2 / s;
  }
  float cx = qx, cy = qy, cz = qz;  // exact raw coords (0.5 * 2x)
  float pcx = w1 * cx, pcy = w1 * cy, pcz = w1 * cz;
  float dcx = e1 * cx, dcy = e1 * cy, dcz = e1 * cz;
  float ax = 0.f, ay = 0.f, az = 0.f;
#pragma unroll 4
  for (int k = 0; k < KNN; ++k) {
    float4 e4 = erw[2 * k + 0];   // broadcast LDS reads
    float4 r4 = erw[2 * k + 1];
    float ex = e4.x, ey = e4.y, ez = e4.z;
    float rx = r4.x, ry = r4.y, rz = r4.z;
    float px = fmaf(w0, ex, fmaf(w2, rx, pcx));
    float py = fmaf(w0, ey, fmaf(w2, ry, pcy));
    float pz = fmaf(w0, ez, fmaf(w2, rz, pcz));
    float dx = fmaf(e0, ex, fmaf(e2, rx, dcx));
    float dy = fmaf(e0, ey, fmaf(e2, ry, dcy));
    float dz = fmaf(e0, ez, fmaf(e2, rz, dcz));
    float dot = fmaf(px, dx, fmaf(py, dy, pz * dz));
    float dns = fmaf(dx, dx, fmaf(dy, dy, dz * dz)) + 1e-6f;
    float r0 = __builtin_amdgcn_rcpf(dns);
    r0 = r0 * fmaf(-dns, r0, 2.0f);          // 1 Newton step
    float f = (dot < 0.f) ? dot * r0 : 0.f;
    ax = fmaf(-f, dx, px) + ax;
    ay = fmaf(-f, dy, py) + ay;
    az = fmaf(-f, dz, pz) + az;
  }
  int pbase = ((q >> 4) * 48) + (q & 15);
  unsigned short* dst = Xp0 + ((size_t)b * P + pbase) * 128 + 2 * o;
  *(unsigned int*)(dst)              = packhl(ax * (1.f / 20.f));
  *(unsigned int*)(dst + 16 * 128)   = packhl(ay * (1.f / 20.f));
  *(unsigned int*)(dst + 32 * 128)   = packhl(az * (1.f / 20.f));
}

// ---------------------------------------------------------------------------
// Shared VNT layer body — per-batch leader computes the pooled bias ONCE.
//
// Round-5 diagnosis: the bias prologue (384 scalar ds_read_b32 of spool per
// thread + 128 strided Wt global loads) ran REDUNDANTLY in all 128 blocks of
// a batch and saturated LDS instruction issue (~14 us/layer chip-wide).
// Now: block nt==0 (leader) waits for all batch peers, computes spool+bias,
// publishes sb[768] to global (coherent stores) and bumps a flag; the other
// 127 blocks wait on the flag and load sb directly (3 loads/thread).
// sb values are bit-identical to what every block computed before.
//
// GSRC=true : stage the X tile [48][K2] from global Xp into LDS.
// GSRC=false: tile already in LDS (repacked in place by the previous layer).
// In-place repack valid because LDO*4 bytes == (256+8)*2 bytes == 528.
// All cross-block data is written by device-scope atomicAdd / agent-scope
// atomic stores (coherent point) and read with relaxed agent-scope loads;
// __syncthreads drains vmcnt before any signal.  No cache-maintenance insts.
// ---------------------------------------------------------------------------
template <int K2, bool HASPOOL, bool LAST, bool GSRC>
__device__ __forceinline__ void vnt_layer_body(
    unsigned short* xt, float* sb, float* spool,
    const unsigned short* __restrict__ Xp, const unsigned short* __restrict__ Wb,
    const float* __restrict__ ps, const float* __restrict__ Wt,
    float* __restrict__ sbg, unsigned int* sbflag,
    float* __restrict__ pool, float* __restrict__ outs,
    unsigned int* wait_cnt, unsigned int* arrive_cnt,
    int b, int nt, int p0, int tid) {
  constexpr int KS = K2 / 32;
  constexpr int LDR = K2 + 8;   // halves; X-tile row stride
  constexpr int LDO = 132;      // floats; out-tile row stride
  float* ot = (float*)xt;
  int w = tid >> 6, lane = tid & 63;
  int q = lane >> 4, cl = lane & 15;

  if constexpr (GSRC) {
    // stage X tile [48][K2] -> LDS
    for (int ch = tid; ch < 48 * (K2 / 8); ch += 256) {
      int rp = ch / (K2 / 8), cc = ch % (K2 / 8);
      *(uint4*)(xt + rp * LDR + cc * 8) =
          *(const uint4*)(Xp + ((size_t)b * P + p0 + rp) * K2 + cc * 8);
    }
  }

  // first A-fragments: global, LDS-independent -> issue before wait/barrier
  bf16x8 acur[2][2], anxt[2][2];
#pragma unroll
  for (int t = 0; t < 2; ++t)
#pragma unroll
    for (int pd = 0; pd < 2; ++pd)
      acur[t][pd] = *(const bf16x8*)(Wb +
          (size_t)(32 * w + 16 * t + 128 * pd + cl) * 32 + q * 8);

  if constexpr (HASPOOL) {
    if (nt == 0) {
      // ---- leader: wait for all batch peers' pool-adds --------------------
      if (tid == 0) {
        while (__hip_atomic_load(wait_cnt, __ATOMIC_RELAXED,
                                 __HIP_MEMORY_SCOPE_AGENT) < (unsigned)BLK_PER_B) {
          __builtin_amdgcn_s_sleep(2);
        }
      }
      __syncthreads();  // wait done + staging/repack visible
      // pooled mean (sum of 8 shadow copies, coherent-point reads) -> LDS
      for (int i = tid; i < 384; i += 256) {
        float x = 0.f;
#pragma unroll
        for (int k = 0; k < 8; ++k)
          x += cohload(&ps[k * 3072 + b * 384 + i]);
        spool[i] = x * (1.f / 2048.f);
      }
      __syncthreads();
      // bias: thread == stacked row m (0..127 = Wn, 128..255 = D)
      float s0 = 0.f, s1 = 0.f, s2 = 0.f;
#pragma unroll 16
      for (int c = 0; c < 128; ++c) {
        float x = Wt[c * 256 + tid];
        s0 = fmaf(x, spool[c * 3 + 0], s0);
        s1 = fmaf(x, spool[c * 3 + 1], s1);
        s2 = fmaf(x, spool[c * 3 + 2], s2);
      }
      sb[tid * 3 + 0] = s0;
      sb[tid * 3 + 1] = s1;
      sb[tid * 3 + 2] = s2;
      cohstore(&sbg[tid * 3 + 0], s0);   // publish to batch peers
      cohstore(&sbg[tid * 3 + 1], s1);
      cohstore(&sbg[tid * 3 + 2], s2);
      __syncthreads();  // drains publish stores (vmcnt 0) + sb LDS visible
      if (tid == 0)
        __hip_atomic_fetch_add(sbflag, 1u, __ATOMIC_RELAXED,
                               __HIP_MEMORY_SCOPE_AGENT);
    } else {
      // ---- follower: wait for the leader's published bias -----------------
      if (tid == 0) {
        while (__hip_atomic_load(sbflag, __ATOMIC_RELAXED,
                                 __HIP_MEMORY_SCOPE_AGENT) < 1u) {
          __builtin_amdgcn_s_sleep(2);
        }
      }
      __syncthreads();  // flag seen + staging/repack visible
      for (int i = tid; i < 768; i += 256) sb[i] = cohload(&sbg[i]);
      __syncthreads();  // sb in LDS for all waves
    }
  } else {
    __syncthreads();  // staging visible to all waves
  }

  f32x4 acc[2][2][3] = {};  // [t][pd][v]

#pragma unroll
  for (int ks = 0; ks < KS; ++ks) {
    if (ks + 1 < KS) {
#pragma unroll
      for (int t = 0; t < 2; ++t)
#pragma unroll
        for (int pd = 0; pd < 2; ++pd)
          anxt[t][pd] = *(const bf16x8*)(Wb +
              (size_t)(32 * w + 16 * t + 128 * pd + cl) * 32 + q * 8 +
              (ks + 1) * 8192);
    }
    bf16x8 bb[3];
#pragma unroll
    for (int v = 0; v < 3; ++v)
      bb[v] = *(const bf16x8*)(xt + (v * 16 + cl) * LDR + ks * 32 + q * 8);
#pragma unroll
    for (int t = 0; t < 2; ++t)
#pragma unroll
      for (int pd = 0; pd < 2; ++pd)
#pragma unroll
        for (int v = 0; v < 3; ++v)
          acc[t][pd][v] = __builtin_amdgcn_mfma_f32_16x16x32_bf16(
              acur[t][pd], bb[v], acc[t][pd][v], 0, 0, 0);
#pragma unroll
    for (int t = 0; t < 2; ++t)
#pragma unroll
      for (int pd = 0; pd < 2; ++pd)
        acur[t][pd] = anxt[t][pd];
  }
  __syncthreads();  // X-tile dead; buffer becomes the fp32 out-tile

#pragma unroll
  for (int t = 0; t < 2; ++t) {
    float res[3][4];
#pragma unroll
    for (int r = 0; r < 4; ++r) {
      int o = 32 * w + 16 * t + 4 * q + r;
      float pv[3], dvv[3];
#pragma unroll
      for (int v = 0; v < 3; ++v) {
        pv[v] = acc[t][0][v][r] + (HASPOOL ? sb[o * 3 + v] : 0.f);
        dvv[v] = acc[t][1][v][r] + (HASPOOL ? sb[(128 + o) * 3 + v] : 0.f);
      }
      float dot = fmaf(pv[0], dvv[0], fmaf(pv[1], dvv[1], pv[2] * dvv[2]));
      float dns = fmaf(dvv[0], dvv[0], fmaf(dvv[1], dvv[1], dvv[2] * dvv[2]));
      float f = (dot < 0.f) ? dot / (dns + 1e-6f) : 0.f;
#pragma unroll
      for (int v = 0; v < 3; ++v) res[v][r] = pv[v] - f * dvv[v];
    }
    int o0 = 32 * w + 16 * t + 4 * q;
#pragma unroll
    for (int v = 0; v < 3; ++v) {
      f32x4 rv = {res[v][0], res[v][1], res[v][2], res[v][3]};
      *(f32x4*)(ot + (v * 16 + cl) * LDO + o0) = rv;
    }
  }
  __syncthreads();

  int shadow = (nt & 7) * 3072;
  for (int s = tid; s < 384; s += 256) {
    int o = s / 3, v = s % 3;
    float a2 = 0.f;
#pragma unroll
    for (int c = 0; c < 16; ++c) a2 += ot[(v * 16 + c) * LDO + o];
    if (LAST) atomicAdd(outs + shadow + b * 384 + s, a2);
    else      atomicAdd(pool + shadow + b * 384 + s, a2);
  }

  // drain this block's atomics (all waves), then ARRIVE before repacking —
  // the next layer's leader can start its wait-release work while we repack.
  __syncthreads();
  if (arrive_cnt != nullptr && tid == 0) {
    __hip_atomic_fetch_add(arrive_cnt, 1u, __ATOMIC_RELAXED,
                           __HIP_MEMORY_SCOPE_AGENT);
  }

  if constexpr (!LAST) {
    // ot reads all completed at the arrive-sync; in-place repack is safe.
    for (int s = tid; s < 1536; s += 256) {
      int pix = s >> 5, c4 = s & 31;
      float4 sv = *(float4*)(ot + pix * LDO + c4 * 4);
      uint4 vv;
      vv.x = packhl(sv.x);
      vv.y = packhl(sv.y);
      vv.z = packhl(sv.z);
      vv.w = packhl(sv.w);
      // same 16 bytes we just read: LDO*4 == 264*2 == 528-byte rows
      *(uint4*)(xt + pix * 264 + c4 * 8) = vv;
    }
  }
}

// ---------------------------------------------------------------------------
// FUSED kernel: layer1 -> (arrive) -> layer2 [leader publishes bias] ->
// (arrive) -> layer3 -> last-block merge.  Activation tile never leaves LDS.
// Co-residency by construction: VGPR<=128, LDS 30208 B -> 4 blocks/CU x 256.
// ---------------------------------------------------------------------------
__global__ __launch_bounds__(256, 4) void vnt_stack_kernel(
    float* __restrict__ ws, float* __restrict__ out) {
  __shared__ __align__(16) char smem[48 * 132 * 4];  // 25344 B, dual-purpose
  __shared__ float sb[768];
  __shared__ float spool[384];
  __shared__ unsigned int last_flag;
  int tid = threadIdx.x;
  int bid = blockIdx.x;
  int b = bid >> 7;
  int nt = bid & 127;
  int p0 = nt * 48;
  unsigned short* xt = (unsigned short*)smem;
  unsigned int* bar = (unsigned int*)(ws + OBAR);
  unsigned int* cnt1 = bar + b * 32;               // per-batch arrive, L1
  unsigned int* cnt2 = bar + 256 + b * 32;         // per-batch arrive, L2
  unsigned int* cntm = bar + 512;                  // global merge counter
  unsigned int* sbf2 = bar + 576 + b * 16;         // sb-published flag, L2
  unsigned int* sbf3 = bar + 704 + b * 16;         // sb-published flag, L3

  // layer1: K2=128, stage from global Xp0; arrive on cnt1; repack into LDS
  vnt_layer_body<128, false, false, true>(
      xt, sb, spool,
      (const unsigned short*)(ws + OXP0), (const unsigned short*)(ws + OWB1),
      nullptr, nullptr, nullptr, nullptr, ws + OPS1, nullptr,
      nullptr, cnt1, b, nt, p0, tid);

  // layer2: K2=256; leader (nt==0) waits cnt1, computes+publishes sb; arrive cnt2
  vnt_layer_body<256, true, false, false>(
      xt, sb, spool,
      nullptr, (const unsigned short*)(ws + OWB2),
      ws + OPS1, ws + OWT2, ws + OSB2 + b * 768, sbf2, ws + OPS2, nullptr,
      cnt1, cnt2, b, nt, p0, tid);

  // layer3: K2=256; leader waits cnt2, publishes sb; outs shadows
  vnt_layer_body<256, true, true, false>(
      xt, sb, spool,
      nullptr, (const unsigned short*)(ws + OWB3),
      ws + OPS2, ws + OWT3, ws + OSB3 + b * 768, sbf3, nullptr, ws + OOUTS,
      cnt2, nullptr, b, nt, p0, tid);

  // last-arriving block performs the merge; everyone else just exits.
  // (body already drained outs atomics at its final __syncthreads)
  if (tid == 0) {
    unsigned old = __hip_atomic_fetch_add(cntm, 1u, __ATOMIC_RELAXED,
                                          __HIP_MEMORY_SCOPE_AGENT);
    last_flag = (old == (unsigned)GRID_VNT - 1) ? 1u : 0u;
  }
  __syncthreads();
  if (last_flag) {
    const float* outs = ws + OOUTS;
    for (int idx = tid; idx < B * 384; idx += 256) {
      float s = 0.f;
#pragma unroll
      for (int k = 0; k < 8; ++k) s += cohload(&outs[k * 3072 + idx]);
      out[idx] = s * (1.f / 2048.f);
    }
  }
}

// ---------------------------------------------------------------------------
// launch
// ---------------------------------------------------------------------------
extern "C" void kernel_launch(void* const* d_in, const int* in_sizes, int n_in,
                              void* d_out, int out_size, void* d_ws, size_t ws_size,
                              hipStream_t stream) {
  (void)in_sizes; (void)n_in; (void)out_size; (void)ws_size;
  const float* pc   = (const float*)d_in[0];
  const float* Wpos = (const float*)d_in[1];
  const float* Dpos = (const float*)d_in[2];
  const float* W1   = (const float*)d_in[3];
  const float* D1   = (const float*)d_in[4];
  const float* W2   = (const float*)d_in[5];
  const float* D2   = (const float*)d_in[6];
  const float* W3   = (const float*)d_in[7];
  const float* D3   = (const float*)d_in[8];
  float* out = (float*)d_out;
  float* ws  = (float*)d_ws;

  // fused prep + KNN + edge + pos layer -> Xp0 (+ packed weights, zeroed
  // shadows AND barrier counters/flags)
  knn_edge_kernel<<<dim3(N / QPW, B), 512, 0, stream>>>(
      pc, Wpos, Dpos, W1, D1, W2, D2, W3, D3, ws);

  // fused 3-layer VNT stack + last-block merge (plain launch; per-batch
  // leader-published pooled bias, arrive/wait counters)
  vnt_stack_kernel<<<GRID_VNT, 256, 0, stream>>>(ws, out);
}

// Round 7
// 157.817 us; speedup vs baseline: 4.3548x; 1.0406x over previous
//
#include <hip/hip_runtime.h>
#include <hip/hip_bf16.h>
#include <math.h>

// ---------------------------------------------------------------------------
// Problem constants
// ---------------------------------------------------------------------------
constexpr int B = 8;
constexpr int N = 2048;
constexpr int KNN = 20;
constexpr int H = 128;
constexpr int P = 3 * N;  // 6144 pixels per batch

// ws layout (float offsets)
constexpr int OSB2   = 0;         // published sb for layer2 [B][768]
constexpr int OWT2   = 8448;      // W2/D2 second-half TRANSPOSED [c<128][m<256]
constexpr int OWT3   = 41216;     // W3/D3 second-half transposed
constexpr int OPS1   = 73984;     // poolsum1 shadows [8][B][128][3] = 24576
constexpr int OPS2   = 98560;     // poolsum2 shadows = 24576
constexpr int OOUTS  = 123136;    // out shadows [8][B][384] = 24576
constexpr int OBAR   = 147712;    // barrier counters/flags (1024 f reserved)
constexpr int OSB3   = 148736;    // published sb for layer3 [B][768]
constexpr int OWB1   = 160000;    // Wbig1 bf16 hi/lo, FRAGMENT-MAJOR (16384 f)
constexpr int OWB2   = 176384;    // Wbig2 fragment-major (32768 f)
constexpr int OWB3   = 209152;    // Wbig3 fragment-major (32768 f)

constexpr int ZERO_BASE = OPS1;   // zeroed region = ps1+ps2+outs+barriers
constexpr int ZERO_CNT  = 74752;  // 73728 shadows + 1024 barrier words
constexpr int PREP_BLOCKS = (ZERO_CNT + 255) / 256;  // 292

constexpr int GRID_VNT  = 1024;   // 4 blocks/CU x 256 CU, exactly co-resident
constexpr int BLK_PER_B = 128;    // blocks per batch (per-batch barrier target)

typedef __attribute__((ext_vector_type(8))) short bf16x8;
typedef __attribute__((ext_vector_type(4))) float f32x4;

__device__ __forceinline__ unsigned short f2bf(float x) {
  __hip_bfloat16 h = __float2bfloat16(x);
  return *(unsigned short*)&h;
}
__device__ __forceinline__ float bf2f(unsigned short u) {
  __hip_bfloat16 h;
  *(unsigned short*)&h = u;
  return __bfloat162float(h);
}
// pack x as (hi, lo) bf16 pair in one uint (hi at lower address)
__device__ __forceinline__ unsigned int packhl(float x) {
  unsigned short hi = f2bf(x);
  float lo = x - bf2f(hi);
  unsigned short ls = f2bf(lo);
  return (unsigned)hi | ((unsigned)ls << 16);
}

// coherent-point read/write (no cache-maintenance instructions)
__device__ __forceinline__ float cohload(const float* p) {
  return __hip_atomic_load(p, __ATOMIC_RELAXED, __HIP_MEMORY_SCOPE_AGENT);
}
__device__ __forceinline__ void cohstore(float* p, float v) {
  __hip_atomic_store(p, v, __ATOMIC_RELAXED, __HIP_MEMORY_SCOPE_AGENT);
}

// ---------------------------------------------------------------------------
// Wave-wide bitonic sort of 64 u64 keys, descending.
// ---------------------------------------------------------------------------
__device__ __forceinline__ void wave_sort_key(unsigned long long& k, int lane) {
#pragma unroll
  for (int kk = 2; kk <= 64; kk <<= 1) {
#pragma unroll
    for (int j = kk >> 1; j > 0; j >>= 1) {
      unsigned long long pk =
          (unsigned long long)__shfl_xor((long long)k, j);
      bool iam_lower   = (lane & j) == 0;
      bool dir_desc    = (lane & kk) == 0;
      bool p_better    = pk > k;
      bool want_better = (dir_desc == iam_lower);
      k = (p_better == want_better) ? pk : k;
    }
  }
}

// ---------------------------------------------------------------------------
// K1: prep — zero shadows/counters + pack weights.  Runs BEFORE the fused
// kernel; the kernel boundary orders zeroing/packing ahead of all barrier
// arrivals and Wb reads (in-kernel zeroing would race early arrivals).
// ---------------------------------------------------------------------------
__global__ __launch_bounds__(256) void prep_kernel(
    const float* __restrict__ W1, const float* __restrict__ D1,
    const float* __restrict__ W2, const float* __restrict__ D2,
    const float* __restrict__ W3, const float* __restrict__ D3,
    float* __restrict__ ws) {
  int tid = threadIdx.x;
  int bid = blockIdx.x;
  {
    int zi = bid * 256 + tid;
    if (zi < ZERO_CNT) ws[ZERO_BASE + zi] = 0.f;
  }
  if (bid < 96) {
    int wv = tid >> 6, lane = tid & 63;
#pragma unroll
    for (int r = 0; r < 2; ++r) {
      int rr = bid * 8 + wv * 2 + r;  // 0..767
      const float* src;
      float* tdst = nullptr;
      unsigned int* pdst;
      int C, Cpack;
      bool norm;
      if (rr < 128)      { src = W1 + rr * 64;            C = 64;  Cpack = 64;  norm = true;
                           pdst = (unsigned int*)(ws + OWB1) + rr * 16; }
      else if (rr < 256) { int m = rr - 128; src = D1 + m * 64;  C = 64;  Cpack = 64;  norm = false;
                           pdst = (unsigned int*)(ws + OWB1) + (m + 128) * 16; }
      else if (rr < 384) { int m = rr - 256; src = W2 + m * 256; C = 256; Cpack = 128; norm = true;
                           pdst = (unsigned int*)(ws + OWB2) + m * 16; tdst = ws + OWT2 + m; }
      else if (rr < 512) { int m = rr - 384; src = D2 + m * 256; C = 256; Cpack = 128; norm = false;
                           pdst = (unsigned int*)(ws + OWB2) + (m + 128) * 16; tdst = ws + OWT2 + 128 + m; }
      else if (rr < 640) { int m = rr - 512; src = W3 + m * 256; C = 256; Cpack = 128; norm = true;
                           pdst = (unsigned int*)(ws + OWB3) + m * 16; tdst = ws + OWT3 + m; }
      else               { int m = rr - 640; src = D3 + m * 256; C = 256; Cpack = 128; norm = false;
                           pdst = (unsigned int*)(ws + OWB3) + (m + 128) * 16; tdst = ws + OWT3 + 128 + m; }
      float s = 1.f;
      if (norm) {
        float a = 0.f;
        for (int i = lane; i < C; i += 64) a += src[i];
#pragma unroll
        for (int off = 32; off > 0; off >>= 1) a += __shfl_xor(a, off);
        s = a;
      }
      for (int i = lane; i < C; i += 64) {
        float val = src[i] / s;  // exact when s==1
        if (i < Cpack) pdst[(i >> 4) * 4096 + (i & 15)] = packhl(val);
        if (tdst && i >= 128) tdst[(i - 128) * 256] = val;
      }
    }
  }
}

// ---------------------------------------------------------------------------
// Shared VNT layer body (X tile ALREADY in LDS — staged from registers by
// the knn phase for L1, or repacked in place by the previous layer).
// Identical math/ordering to the verified per-layer kernel.
// In-place repack valid because LDO*4 bytes == (256+8)*2 bytes == 528.
// ---------------------------------------------------------------------------
template <int K2, bool HASPOOL, bool LAST>
__device__ __forceinline__ void vnt_layer_body(
    unsigned short* xt, float* sb, float* spool,
    const unsigned short* __restrict__ Wb,
    const float* __restrict__ ps, const float* __restrict__ Wt,
    float* __restrict__ sbg, unsigned int* sbflag,
    float* __restrict__ pool, float* __restrict__ outs,
    unsigned int* wait_cnt, unsigned int* arrive_cnt,
    int b, int nt, int p0, int tid) {
  constexpr int KS = K2 / 32;
  constexpr int LDR = K2 + 8;   // halves; X-tile row stride
  constexpr int LDO = 132;      // floats; out-tile row stride
  float* ot = (float*)xt;
  int w = tid >> 6, lane = tid & 63;
  int q = lane >> 4, cl = lane & 15;

  // first A-fragments: global, LDS-independent -> issue before wait/barrier
  bf16x8 acur[2][2], anxt[2][2];
#pragma unroll
  for (int t = 0; t < 2; ++t)
#pragma unroll
    for (int pd = 0; pd < 2; ++pd)
      acur[t][pd] = *(const bf16x8*)(Wb +
          (size_t)(32 * w + 16 * t + 128 * pd + cl) * 32 + q * 8);

  if constexpr (HASPOOL) {
    if (nt == 0) {
      // ---- leader: wait for all batch peers' pool-adds --------------------
      if (tid == 0) {
        while (__hip_atomic_load(wait_cnt, __ATOMIC_RELAXED,
                                 __HIP_MEMORY_SCOPE_AGENT) < (unsigned)BLK_PER_B) {
          __builtin_amdgcn_s_sleep(2);
        }
      }
      __syncthreads();  // wait done + tile visible
      for (int i = tid; i < 384; i += 256) {
        float x = 0.f;
#pragma unroll
        for (int k = 0; k < 8; ++k)
          x += cohload(&ps[k * 3072 + b * 384 + i]);
        spool[i] = x * (1.f / 2048.f);
      }
      __syncthreads();
      // bias: thread == stacked row m (0..127 = Wn, 128..255 = D)
      float s0 = 0.f, s1 = 0.f, s2 = 0.f;
#pragma unroll 16
      for (int c = 0; c < 128; ++c) {
        float x = Wt[c * 256 + tid];
        s0 = fmaf(x, spool[c * 3 + 0], s0);
        s1 = fmaf(x, spool[c * 3 + 1], s1);
        s2 = fmaf(x, spool[c * 3 + 2], s2);
      }
      sb[tid * 3 + 0] = s0;
      sb[tid * 3 + 1] = s1;
      sb[tid * 3 + 2] = s2;
      cohstore(&sbg[tid * 3 + 0], s0);   // publish to batch peers
      cohstore(&sbg[tid * 3 + 1], s1);
      cohstore(&sbg[tid * 3 + 2], s2);
      __syncthreads();  // drains publish stores (vmcnt 0) + sb LDS visible
      if (tid == 0)
        __hip_atomic_fetch_add(sbflag, 1u, __ATOMIC_RELAXED,
                               __HIP_MEMORY_SCOPE_AGENT);
    } else {
      // ---- follower: wait for the leader's published bias -----------------
      if (tid == 0) {
        while (__hip_atomic_load(sbflag, __ATOMIC_RELAXED,
                                 __HIP_MEMORY_SCOPE_AGENT) < 1u) {
          __builtin_amdgcn_s_sleep(2);
        }
      }
      __syncthreads();  // flag seen + tile visible
      for (int i = tid; i < 768; i += 256) sb[i] = cohload(&sbg[i]);
      __syncthreads();  // sb in LDS for all waves
    }
  } else {
    __syncthreads();  // tile visible to all waves
  }

  f32x4 acc[2][2][3] = {};  // [t][pd][v]

#pragma unroll
  for (int ks = 0; ks < KS; ++ks) {
    if (ks + 1 < KS) {
#pragma unroll
      for (int t = 0; t < 2; ++t)
#pragma unroll
        for (int pd = 0; pd < 2; ++pd)
          anxt[t][pd] = *(const bf16x8*)(Wb +
              (size_t)(32 * w + 16 * t + 128 * pd + cl) * 32 + q * 8 +
              (ks + 1) * 8192);
    }
    bf16x8 bb[3];
#pragma unroll
    for (int v = 0; v < 3; ++v)
      bb[v] = *(const bf16x8*)(xt + (v * 16 + cl) * LDR + ks * 32 + q * 8);
#pragma unroll
    for (int t = 0; t < 2; ++t)
#pragma unroll
      for (int pd = 0; pd < 2; ++pd)
#pragma unroll
        for (int v = 0; v < 3; ++v)
          acc[t][pd][v] = __builtin_amdgcn_mfma_f32_16x16x32_bf16(
              acur[t][pd], bb[v], acc[t][pd][v], 0, 0, 0);
#pragma unroll
    for (int t = 0; t < 2; ++t)
#pragma unroll
      for (int pd = 0; pd < 2; ++pd)
        acur[t][pd] = anxt[t][pd];
  }
  __syncthreads();  // X-tile dead; buffer becomes the fp32 out-tile

#pragma unroll
  for (int t = 0; t < 2; ++t) {
    float res[3][4];
#pragma unroll
    for (int r = 0; r < 4; ++r) {
      int o = 32 * w + 16 * t + 4 * q + r;
      float pv[3], dvv[3];
#pragma unroll
      for (int v = 0; v < 3; ++v) {
        pv[v] = acc[t][0][v][r] + (HASPOOL ? sb[o * 3 + v] : 0.f);
        dvv[v] = acc[t][1][v][r] + (HASPOOL ? sb[(128 + o) * 3 + v] : 0.f);
      }
      float dot = fmaf(pv[0], dvv[0], fmaf(pv[1], dvv[1], pv[2] * dvv[2]));
      float dns = fmaf(dvv[0], dvv[0], fmaf(dvv[1], dvv[1], dvv[2] * dvv[2]));
      float f = (dot < 0.f) ? dot / (dns + 1e-6f) : 0.f;
#pragma unroll
      for (int v = 0; v < 3; ++v) res[v][r] = pv[v] - f * dvv[v];
    }
    int o0 = 32 * w + 16 * t + 4 * q;
#pragma unroll
    for (int v = 0; v < 3; ++v) {
      f32x4 rv = {res[v][0], res[v][1], res[v][2], res[v][3]};
      *(f32x4*)(ot + (v * 16 + cl) * LDO + o0) = rv;
    }
  }
  __syncthreads();

  int shadow = (nt & 7) * 3072;
  for (int s = tid; s < 384; s += 256) {
    int o = s / 3, v = s % 3;
    float a2 = 0.f;
#pragma unroll
    for (int c = 0; c < 16; ++c) a2 += ot[(v * 16 + c) * LDO + o];
    if (LAST) atomicAdd(outs + shadow + b * 384 + s, a2);
    else      atomicAdd(pool + shadow + b * 384 + s, a2);
  }

  // drain this block's atomics (all waves), then ARRIVE before repacking
  __syncthreads();
  if (arrive_cnt != nullptr && tid == 0) {
    __hip_atomic_fetch_add(arrive_cnt, 1u, __ATOMIC_RELAXED,
                           __HIP_MEMORY_SCOPE_AGENT);
  }

  if constexpr (!LAST) {
    for (int s = tid; s < 1536; s += 256) {
      int pix = s >> 5, c4 = s & 31;
      float4 sv = *(float4*)(ot + pix * LDO + c4 * 4);
      uint4 vv;
      vv.x = packhl(sv.x);
      vv.y = packhl(sv.y);
      vv.z = packhl(sv.z);
      vv.w = packhl(sv.w);
      // same 16 bytes we just read: LDO*4 == 264*2 == 528-byte rows
      *(uint4*)(xt + pix * 264 + c4 * 8) = vv;
    }
  }
}

// ---------------------------------------------------------------------------
// K2 FUSED: KNN+edge (16 queries/block, 4/wave sequential) -> X tile written
// from registers into LDS (no global Xp0) -> 3 VNT layers -> last-block merge.
// LDS union: knn view [spt 32768 | sphase 4x640] = 35328 B;
//            vnt view [xt 25344 | sb 3072 | spool 1536] = 29952 B.
// 4 blocks/CU x 256 CUs = 1024 blocks co-resident by construction
// (LDS 35.3K <= 40K, VGPR <= 128 via __launch_bounds__(256,4), 16 waves/CU).
// ---------------------------------------------------------------------------
__global__ __launch_bounds__(256, 4) void fused_kernel(
    const float* __restrict__ pc, const float* __restrict__ Wpos,
    const float* __restrict__ Dp, float* __restrict__ ws,
    float* __restrict__ out) {
  __shared__ __align__(16) char U[35328];
  __shared__ unsigned int last_flag;
  int tid = threadIdx.x, wv = tid >> 6, lane = tid & 63;
  int bid = blockIdx.x;
  int b = bid >> 7;
  int nt = bid & 127;
  int p0 = nt * 48;

  float4* spt = (float4*)U;
  unsigned char* sph = (unsigned char*)(U + 32768) + wv * 640;
  unsigned short* sbufw = (unsigned short*)sph;
  float4* erw = (float4*)sph;
  unsigned short* xt = (unsigned short*)U;
  float* sb = (float*)(U + 25344);
  float* spool = (float*)(U + 28416);

  unsigned int* bar = (unsigned int*)(ws + OBAR);
  unsigned int* cnt1 = bar + b * 32;               // per-batch arrive, L1
  unsigned int* cnt2 = bar + 256 + b * 32;         // per-batch arrive, L2
  unsigned int* cntm = bar + 512;                  // global merge counter
  unsigned int* sbf2 = bar + 576 + b * 16;         // sb-published flag, L2
  unsigned int* sbf3 = bar + 704 + b * 16;         // sb-published flag, L3

  // hoisted edge-phase weight loads (latency hidden under spt staging)
  int o = lane;
  float w0 = Wpos[o * 3 + 0], w1 = Wpos[o * 3 + 1], w2 = Wpos[o * 3 + 2];
  float e0 = Dp[o * 3 + 0], e1 = Dp[o * 3 + 1], e2 = Dp[o * 3 + 2];

  // ---- stage point cloud ---------------------------------------------------
  const float* pcb = pc + (size_t)b * N * 3;
  for (int i = tid; i < N; i += 256) {
    float x = pcb[i * 3 + 0], y = pcb[i * 3 + 1], z = pcb[i * 3 + 2];
    float xx = __fadd_rn(__fadd_rn(__fmul_rn(x, x), __fmul_rn(y, y)), __fmul_rn(z, z));
    spt[i] = make_float4(2.f * x, 2.f * y, 2.f * z, xx);
  }
  __syncthreads();

  // normalize pos weights once (query-independent, exact same math)
  {
    float s = (w0 + w2) + w1;
    w0 = w0 / s; w1 = w1 / s; w2 = w2 / s;
  }

  unsigned rx0[4], rx1[4], rx2[4];  // packed edge-layer results per query

#pragma unroll
  for (int j = 0; j < 4; ++j) {
    int q = nt * 16 + wv * 4 + j;
    float4 qp = spt[q];
    float qx = 0.5f * qp.x, qy = 0.5f * qp.y, qz = 0.5f * qp.z, qxx = qp.w;

    float dv[32];
    float lmax = -INFINITY;
#pragma unroll
    for (int i = 0; i < 32; ++i) {
      float4 m = spt[i * 64 + lane];
      float A = __fadd_rn(__fadd_rn(__fmul_rn(m.x, qx), __fmul_rn(m.y, qy)),
                          __fmul_rn(m.z, qz));
      float d = __fsub_rn(__fsub_rn(A, qxx), m.w);
      dv[i] = d;
      lmax = fmaxf(lmax, d);
    }

    // value-only bitonic sort (descending) of the 64 lane-maxes; take #19
    float sv = lmax;
#pragma unroll
    for (int k = 2; k <= 64; k <<= 1) {
#pragma unroll
      for (int jj = k >> 1; jj > 0; jj >>= 1) {
        float pv = __shfl_xor(sv, jj);
        bool keep_max = ((lane & k) == 0) == ((lane & jj) == 0);
        sv = keep_max ? fmaxf(sv, pv) : fminf(sv, pv);
      }
    }
    float tval = __shfl(sv, 19);

    // registerized compact: per-lane survivor mask + shfl prefix scan
    unsigned msk = 0u;
#pragma unroll
    for (int i = 0; i < 32; ++i) msk |= (dv[i] >= tval) ? (1u << i) : 0u;
    int cnt = __popc(msk);
    int scan = cnt;
#pragma unroll
    for (int off = 1; off < 64; off <<= 1) {
      int t = __shfl_up(scan, off);
      scan += (lane >= off) ? t : 0;
    }
    int S = __shfl(scan, 63);
    int pos = scan - cnt;
    unsigned mm = msk;
    while (mm) {
      int i = __ffs(mm) - 1;
      mm &= mm - 1;
      if (pos < 192) sbufw[pos] = (unsigned short)(i * 64 + lane);
      ++pos;
    }

    auto distOf = [&](int m) -> float {
      float4 mp = spt[m];
      float A = __fadd_rn(__fadd_rn(__fmul_rn(mp.x, qx), __fmul_rn(mp.y, qy)),
                          __fmul_rn(mp.z, qz));
      return __fsub_rn(__fsub_rn(A, qxx), mp.w);
    };
    auto mkkey = [&](int m) -> unsigned long long {
      float d = distOf(m);
      unsigned u = __float_as_uint(d);
      u ^= (u >> 31) ? 0xFFFFFFFFu : 0x80000000u;
      return ((unsigned long long)u << 32) | (unsigned)(~m);
    };

    unsigned long long key = 0ULL;
    if (S <= 64) {
      if (lane < S) key = mkkey(sbufw[lane]);
      wave_sort_key(key, lane);
    } else if (S <= 192) {
      int p2 = 0;
      while (p2 < S) {
        if (lane >= KNN) {
          int t = p2 + lane - KNN;
          key = (t < S) ? mkkey(sbufw[t]) : 0ULL;
        }
        wave_sort_key(key, lane);
        p2 += 64 - KNN;
      }
    } else {
      int p2 = 0;
      while (p2 < N) {
        if (lane >= KNN) {
          int t = p2 + lane - KNN;
          key = (t < N) ? mkkey(t) : 0ULL;
        }
        wave_sort_key(key, lane);
        p2 += 64 - KNN;
      }
    }
    int cm = ~((unsigned)key);  // valid in lanes 0..19

    // edge geometry precompute: lane k<20 computes e/r once
    if (lane < KNN) {
      float4 t = spt[cm];
      float nx = 0.5f * t.x, ny = 0.5f * t.y, nz = 0.5f * t.z;
      float ex = nx - qx, ey = ny - qy, ez = nz - qz;
      float rrx = ny * qz - nz * qy;
      float rry = nz * qx - nx * qz;
      float rrz = nx * qy - ny * qx;
      erw[2 * lane + 0] = make_float4(ex, ey, ez, 0.f);
      erw[2 * lane + 1] = make_float4(rrx, rry, rrz, 0.f);
    }

    // edge + pos layer (lane o = channel o)
    float cx = qx, cy = qy, cz = qz;
    float pcx = w1 * cx, pcy = w1 * cy, pcz = w1 * cz;
    float dcx = e1 * cx, dcy = e1 * cy, dcz = e1 * cz;
    float ax = 0.f, ay = 0.f, az = 0.f;
#pragma unroll 4
    for (int k = 0; k < KNN; ++k) {
      float4 e4 = erw[2 * k + 0];
      float4 r4 = erw[2 * k + 1];
      float ex = e4.x, ey = e4.y, ez = e4.z;
      float rrx = r4.x, rry = r4.y, rrz = r4.z;
      float px = fmaf(w0, ex, fmaf(w2, rrx, pcx));
      float py = fmaf(w0, ey, fmaf(w2, rry, pcy));
      float pz = fmaf(w0, ez, fmaf(w2, rrz, pcz));
      float dx = fmaf(e0, ex, fmaf(e2, rrx, dcx));
      float dy = fmaf(e0, ey, fmaf(e2, rry, dcy));
      float dz = fmaf(e0, ez, fmaf(e2, rrz, dcz));
      float dot = fmaf(px, dx, fmaf(py, dy, pz * dz));
      float dns = fmaf(dx, dx, fmaf(dy, dy, dz * dz)) + 1e-6f;
      float r0 = __builtin_amdgcn_rcpf(dns);
      r0 = r0 * fmaf(-dns, r0, 2.0f);
      float f = (dot < 0.f) ? dot * r0 : 0.f;
      ax = fmaf(-f, dx, px) + ax;
      ay = fmaf(-f, dy, py) + ay;
      az = fmaf(-f, dz, pz) + az;
    }
    rx0[j] = packhl(ax * (1.f / 20.f));
    rx1[j] = packhl(ay * (1.f / 20.f));
    rx2[j] = packhl(az * (1.f / 20.f));
  }

  __syncthreads();  // spt/sphase dead everywhere; LDS becomes the X tile

  // write L1 X tile [48][128] bf16 hi/lo from registers (LDR = 136 halves)
#pragma unroll
  for (int j = 0; j < 4; ++j) {
    int row = wv * 4 + j;  // q & 15
    *(unsigned int*)(xt + (row + 0)  * 136 + 2 * o) = rx0[j];
    *(unsigned int*)(xt + (row + 16) * 136 + 2 * o) = rx1[j];
    *(unsigned int*)(xt + (row + 32) * 136 + 2 * o) = rx2[j];
  }
  // (tile-visibility barrier is inside the layer body)

  // layer1: K2=128, tile in LDS; arrive on cnt1; repack into LDS
  vnt_layer_body<128, false, false>(
      xt, sb, spool, (const unsigned short*)(ws + OWB1),
      nullptr, nullptr, nullptr, nullptr, ws + OPS1, nullptr,
      nullptr, cnt1, b, nt, p0, tid);

  // layer2: K2=256; leader (nt==0) waits cnt1, computes+publishes sb; arrive cnt2
  vnt_layer_body<256, true, false>(
      xt, sb, spool, (const unsigned short*)(ws + OWB2),
      ws + OPS1, ws + OWT2, ws + OSB2 + b * 768, sbf2, ws + OPS2, nullptr,
      cnt1, cnt2, b, nt, p0, tid);

  // layer3: K2=256; leader waits cnt2, publishes sb; outs shadows
  vnt_layer_body<256, true, true>(
      xt, sb, spool, (const unsigned short*)(ws + OWB3),
      ws + OPS2, ws + OWT3, ws + OSB3 + b * 768, sbf3, nullptr, ws + OOUTS,
      cnt2, nullptr, b, nt, p0, tid);

  // last-arriving block performs the merge; everyone else just exits.
  if (tid == 0) {
    unsigned old = __hip_atomic_fetch_add(cntm, 1u, __ATOMIC_RELAXED,
                                          __HIP_MEMORY_SCOPE_AGENT);
    last_flag = (old == (unsigned)GRID_VNT - 1) ? 1u : 0u;
  }
  __syncthreads();
  if (last_flag) {
    const float* outs = ws + OOUTS;
    for (int idx = tid; idx < B * 384; idx += 256) {
      float s = 0.f;
#pragma unroll
      for (int k = 0; k < 8; ++k) s += cohload(&outs[k * 3072 + idx]);
      out[idx] = s * (1.f / 2048.f);
    }
  }
}

// ---------------------------------------------------------------------------
// launch
// ---------------------------------------------------------------------------
extern "C" void kernel_launch(void* const* d_in, const int* in_sizes, int n_in,
                              void* d_out, int out_size, void* d_ws, size_t ws_size,
                              hipStream_t stream) {
  (void)in_sizes; (void)n_in; (void)out_size; (void)ws_size;
  const float* pc   = (const float*)d_in[0];
  const float* Wpos = (const float*)d_in[1];
  const float* Dpos = (const float*)d_in[2];
  const float* W1   = (const float*)d_in[3];
  const float* D1   = (const float*)d_in[4];
  const float* W2   = (const float*)d_in[5];
  const float* D2   = (const float*)d_in[6];
  const float* W3   = (const float*)d_in[7];
  const float* D3   = (const float*)d_in[8];
  float* out = (float*)d_out;
  float* ws  = (float*)d_ws;

  // K1: zero shadows/counters + pack weights (orders ahead of fused kernel)
  prep_kernel<<<PREP_BLOCKS, 256, 0, stream>>>(W1, D1, W2, D2, W3, D3, ws);

  // K2: fused KNN+edge+3-layer VNT stack + last-block merge
  fused_kernel<<<GRID_VNT, 256, 0, stream>>>(pc, Wpos, Dpos, ws, out);
}